// Round 7
// baseline (1464.969 us; speedup 1.0000x reference)
//
#include <hip/hip_runtime.h>

#define N_NODES 100000
#define N_EDGES 1600000
#define NF 128
#define NC 16
#define NH 2
#define HC 32   // NH*NC
#define NL 2
#define NED 4
#define EPS 1e-5f
#define NEG 0.2f
#define NBUCK 196                    // ceil(N_NODES / 512)
#define P1_CHUNK 4096
#define P1_BLKS ((N_EDGES + P1_CHUNK - 1) / P1_CHUNK)   // 391
#define AGG_BLKS ((N_NODES + 7) / 8)               // 12500
#define MID_BLKS ((N_NODES + 15) / 16)             // 6250

// ---- bf16 helpers (manual, RTN-even) -----------------------------------------
__device__ __forceinline__ unsigned short f2bf(float f) {
    unsigned int u = __float_as_uint(f);
    u += 0x7fffu + ((u >> 16) & 1u);
    return (unsigned short)(u >> 16);
}
__device__ __forceinline__ float bf2f(unsigned short u) {
    return __uint_as_float(((unsigned int)u) << 16);
}

// ---------------- embed: h = relu(node_LN(x @ W + b)) ; jk = h ----------------
__global__ __launch_bounds__(256) void k_embed(
    const float* __restrict__ x, const float* __restrict__ W,
    const float* __restrict__ b, const float* __restrict__ lnw,
    const float* __restrict__ lnb, float* __restrict__ h, float* __restrict__ jk)
{
    __shared__ float Ws[NF * NC];
    __shared__ float xs[16][NF + 4];
    const int t = threadIdx.x;
    for (int i = t; i < NF * NC; i += 256) Ws[i] = W[i];
    const int n0 = blockIdx.x * 16;
    for (int i = t; i < 16 * NF; i += 256) {
        int r = i >> 7, f = i & (NF - 1);
        int n = n0 + r;
        xs[r][f] = (n < N_NODES) ? x[(size_t)n * NF + f] : 0.f;
    }
    __syncthreads();
    const int r = t >> 4;
    const int c = t & 15;
    const int n = n0 + r;
    float acc = b[c];
#pragma unroll 16
    for (int f = 0; f < NF; ++f) acc += xs[r][f] * Ws[f * NC + c];
    float s = acc;
    for (int m = 8; m >= 1; m >>= 1) s += __shfl_xor(s, m, 16);
    float mu = s * (1.f / 16.f);
    float d = acc - mu;
    float v = d * d;
    for (int m = 8; m >= 1; m >>= 1) v += __shfl_xor(v, m, 16);
    float inv = rsqrtf(v * (1.f / 16.f) + EPS);
    float out = fmaxf(d * inv * lnw[c] + lnb[c], 0.f);
    if (n < N_NODES) {
        h[(size_t)n * NC + c]  = out;
        jk[(size_t)n * NC + c] = out;
    }
}

// ---- bucket histogram (bucket = dst >> 9) + last-block scan ------------------
__global__ __launch_bounds__(256) void k_bhist(
    const int* __restrict__ dst, int* __restrict__ bcnt, unsigned* __restrict__ ctr,
    int* __restrict__ bbase, int* __restrict__ bcur)
{
    __shared__ int hist[256];
    __shared__ bool amLast;
    const int t = threadIdx.x;
    hist[t] = 0;
    __syncthreads();
    const int e0 = blockIdx.x * P1_CHUNK;
    const int cnt = min(P1_CHUNK, N_EDGES - e0);
    for (int i = t; i < cnt; i += 256)
        atomicAdd(&hist[dst[e0 + i] >> 9], 1);
    __syncthreads();
    if (hist[t] > 0) atomicAdd(&bcnt[t], hist[t]);
    __syncthreads();   // all this block's global atomics drained before ticket
    if (t == 0) {
        __threadfence();
        amLast = (atomicAdd(ctr, 1u) == (unsigned)gridDim.x - 1u);
    }
    __syncthreads();
    if (amLast) {
        __threadfence();
        int v0 = ((volatile int*)bcnt)[t];
        __shared__ int tmp[256];
        tmp[t] = v0;
        __syncthreads();
        for (int off = 1; off < 256; off <<= 1) {
            int v = (t >= off) ? tmp[t - off] : 0;
            __syncthreads();
            tmp[t] += v;
            __syncthreads();
        }
        int excl = tmp[t] - v0;
        bbase[t] = excl;
        bcur[t]  = excl;
        if (t == 255) bbase[256] = tmp[t];   // == N_EDGES
    }
}

// ---- pass1: LDS-staged bucket scatter; relays eattr (chunk-local gather) -----
// staged payload: {src, (e<<9)|dst_local}; e < 2^21, dst_local < 512
__global__ __launch_bounds__(256) void k_pass1(
    const int* __restrict__ src, const int* __restrict__ dst,
    const float4* __restrict__ ea4, int* __restrict__ bcur,
    int2* __restrict__ tmp_se, float4* __restrict__ tmp_ea)
{
    __shared__ int2 stage[P1_CHUNK];                 // 32 KB
    __shared__ unsigned char bstage[P1_CHUNK];       // 4 KB
    __shared__ int hist[256];
    __shared__ int exc[256];
    __shared__ int gbase[256];
    __shared__ int scanbuf[256];
    const int t = threadIdx.x;
    const int e0 = blockIdx.x * P1_CHUNK;
    const int cnt = min(P1_CHUNK, N_EDGES - e0);
    hist[t] = 0;
    __syncthreads();
    int mys[16], myb[16], myp[16];
    int nv = 0;
#pragma unroll
    for (int k = 0; k < 16; ++k) {
        int i = k * 256 + t;
        if (i < cnt) {
            int e = e0 + i;
            int d = dst[e];
            mys[nv] = src[e];
            myb[nv] = d >> 9;
            myp[nv] = (e << 9) | (d & 511);
            atomicAdd(&hist[d >> 9], 1);
            ++nv;
        }
    }
    __syncthreads();
    int hv = hist[t];
    scanbuf[t] = hv;
    __syncthreads();
    for (int off = 1; off < 256; off <<= 1) {
        int v = (t >= off) ? scanbuf[t - off] : 0;
        __syncthreads();
        scanbuf[t] += v;
        __syncthreads();
    }
    int ex = scanbuf[t] - hv;
    hist[t] = ex;            // becomes local cursor
    exc[t]  = ex;
    __syncthreads();
    for (int k = 0; k < nv; ++k) {
        int pos = atomicAdd(&hist[myb[k]], 1);
        stage[pos]  = make_int2(mys[k], myp[k]);
        bstage[pos] = (unsigned char)myb[k];
    }
    __syncthreads();
    {
        int c = hist[t] - exc[t];
        gbase[t] = (c > 0) ? atomicAdd(&bcur[t], c) : 0;
    }
    __syncthreads();
    // flush: bucket runs -> contiguous global slots; ea4 gather stays in the
    // chunk's 64 KB window (L2-resident streaming)
    for (int i = t; i < cnt; i += 256) {
        int b = bstage[i];
        int2 se = stage[i];
        int e = (int)(((unsigned int)se.y) >> 9);
        int gpos = gbase[b] + (i - exc[b]);
        tmp_se[gpos] = se;
        tmp_ea[gpos] = ea4[e];
    }
}

// ---- pass2: one block per bucket; per-dst LDS hist+scan -> offsets + CSR -----
__global__ __launch_bounds__(256) void k_pass2(
    const int* __restrict__ bbase, const int2* __restrict__ tmp_se,
    const float4* __restrict__ tmp_ea,
    int* __restrict__ offsets, int* __restrict__ csr_src, float4* __restrict__ csr_ea)
{
    __shared__ int hist[512];
    __shared__ int cur[512];
    __shared__ int scanbuf[256];
    const int b = blockIdx.x, t = threadIdx.x;
    const int ebeg = bbase[b], eend = bbase[b + 1];
    hist[t] = 0; hist[t + 256] = 0;
    __syncthreads();
    for (int i = ebeg + t; i < eend; i += 256)
        atomicAdd(&hist[tmp_se[i].y & 511], 1);
    __syncthreads();
    int a0 = hist[2 * t], a1 = hist[2 * t + 1];
    int pair = a0 + a1;
    scanbuf[t] = pair;
    __syncthreads();
    for (int off = 1; off < 256; off <<= 1) {
        int v = (t >= off) ? scanbuf[t - off] : 0;
        __syncthreads();
        scanbuf[t] += v;
        __syncthreads();
    }
    int ex2 = scanbuf[t] - pair;
    cur[2 * t]     = ex2;
    cur[2 * t + 1] = ex2 + a0;
    __syncthreads();
    const int n0 = b * 512;
#pragma unroll
    for (int k = 0; k < 2; ++k) {
        int i = t + k * 256;
        int n = n0 + i;
        if (n < N_NODES) offsets[n] = ebeg + cur[i];
    }
    if (b == NBUCK - 1 && t == 0) offsets[N_NODES] = N_EDGES;
    __syncthreads();
    // permute (writes stay inside this bucket's L2-resident window)
    for (int i = ebeg + t; i < eend; i += 256) {
        int2 se = tmp_se[i];
        float4 ea = tmp_ea[i];
        int dl = se.y & 511;
        int pos = ebeg + atomicAdd(&cur[dl], 1);
        csr_src[pos] = se.x;
        csr_ea[pos]  = ea;
    }
}

// ---- per-layer: xl/xr transforms (bf16 out) ----------------------------------
__global__ __launch_bounds__(256) void k_trans(
    const float* __restrict__ h, const float* __restrict__ Wl, const float* __restrict__ bl,
    const float* __restrict__ Wr, const float* __restrict__ br,
    unsigned short* __restrict__ xl, unsigned short* __restrict__ xr)
{
    __shared__ float Wls[NC * HC], Wrs[NC * HC];
    __shared__ float hs[8][NC + 1];
    const int t = threadIdx.x;
    for (int i = t; i < NC * HC; i += 256) { Wls[i] = Wl[i]; Wrs[i] = Wr[i]; }
    const int n0 = blockIdx.x * 8;
    for (int i = t; i < 8 * NC; i += 256) {
        int r = i >> 4, c = i & 15;
        int n = n0 + r;
        hs[r][c] = (n < N_NODES) ? h[(size_t)n * NC + c] : 0.f;
    }
    __syncthreads();
    const int r = t >> 5;
    const int j = t & 31;
    const int n = n0 + r;
    float al = bl[j], ar = br[j];
#pragma unroll
    for (int c = 0; c < NC; ++c) {
        float hv = hs[r][c];
        al += hv * Wls[c * HC + j];
        ar += hv * Wrs[c * HC + j];
    }
    if (n < N_NODES) {
        xl[(size_t)n * HC + j] = f2bf(al);
        xr[(size_t)n * HC + j] = f2bf(ar);
    }
}

__device__ __forceinline__ float head_sum(float p) {
    p += __shfl_xor(p, 1, 16);
    p += __shfl_xor(p, 2, 16);
    p += __shfl_xor(p, 4, 16);
    p += __shfl_xor(p, 8, 16);
    return p;
}

// ---- aggregation: sequential CSR reads, unroll-4; last block reduces stats ---
__global__ __launch_bounds__(256) void k_agg(
    const int* __restrict__ offsets, const int* __restrict__ csr_src,
    const float4* __restrict__ csr_ea,
    const float* __restrict__ We, const float* __restrict__ att,
    const float* __restrict__ gat_b,
    const unsigned short* __restrict__ xl, const unsigned short* __restrict__ xr,
    float* __restrict__ g, float2* __restrict__ part,
    unsigned* __restrict__ ctr, double* __restrict__ stats)
{
    __shared__ float Wes[NED * HC];
    __shared__ float atts[HC], gbs[HC];
    __shared__ bool amLast;
    const int t = threadIdx.x;
    if (t < NED * HC) Wes[t] = We[t];
    if (t < HC) { atts[t] = att[t]; gbs[t] = gat_b[t]; }
    __syncthreads();
    const int grp = t >> 5;
    const int j   = t & 31;
    const int d = blockIdx.x * 8 + grp;
    float gv = 0.f;
    if (d < N_NODES) {
        const float aj = atts[j];
        const float w0 = Wes[j], w1 = Wes[HC + j], w2 = Wes[2 * HC + j], w3 = Wes[3 * HC + j];
        const float xld = bf2f(xl[(size_t)d * HC + j]);
        const float xrd = bf2f(xr[(size_t)d * HC + j]);
        // self-loop (ew = 0); logits tiny: exp without segment-max is exact enough
        float m = xld + xrd;
        m = (m > 0.f) ? m : NEG * m;
        float eh = __expf(head_sum(m * aj));
        float acc = eh * xld;
        float den = eh;
        const int base = offsets[d];
        const int deg  = offsets[d + 1] - base;
        int k = 0;
        for (; k + 4 <= deg; k += 4) {
            const int b0 = base + k;
            const int s0 = csr_src[b0],     s1 = csr_src[b0 + 1];
            const int s2 = csr_src[b0 + 2], s3 = csr_src[b0 + 3];
            const float4 e0 = csr_ea[b0],     e1 = csr_ea[b0 + 1];
            const float4 e2 = csr_ea[b0 + 2], e3 = csr_ea[b0 + 3];
            const float x0 = bf2f(xl[(size_t)s0 * HC + j]);
            const float x1 = bf2f(xl[(size_t)s1 * HC + j]);
            const float x2 = bf2f(xl[(size_t)s2 * HC + j]);
            const float x3 = bf2f(xl[(size_t)s3 * HC + j]);
            float m0 = x0 + xrd + e0.x * w0 + e0.y * w1 + e0.z * w2 + e0.w * w3;
            float m1 = x1 + xrd + e1.x * w0 + e1.y * w1 + e1.z * w2 + e1.w * w3;
            float m2 = x2 + xrd + e2.x * w0 + e2.y * w1 + e2.z * w2 + e2.w * w3;
            float m3 = x3 + xrd + e3.x * w0 + e3.y * w1 + e3.z * w2 + e3.w * w3;
            m0 = (m0 > 0.f) ? m0 : NEG * m0;
            m1 = (m1 > 0.f) ? m1 : NEG * m1;
            m2 = (m2 > 0.f) ? m2 : NEG * m2;
            m3 = (m3 > 0.f) ? m3 : NEG * m3;
            float p0 = m0 * aj, p1 = m1 * aj, p2 = m2 * aj, p3 = m3 * aj;
            p0 += __shfl_xor(p0, 1, 16); p1 += __shfl_xor(p1, 1, 16);
            p2 += __shfl_xor(p2, 1, 16); p3 += __shfl_xor(p3, 1, 16);
            p0 += __shfl_xor(p0, 2, 16); p1 += __shfl_xor(p1, 2, 16);
            p2 += __shfl_xor(p2, 2, 16); p3 += __shfl_xor(p3, 2, 16);
            p0 += __shfl_xor(p0, 4, 16); p1 += __shfl_xor(p1, 4, 16);
            p2 += __shfl_xor(p2, 4, 16); p3 += __shfl_xor(p3, 4, 16);
            p0 += __shfl_xor(p0, 8, 16); p1 += __shfl_xor(p1, 8, 16);
            p2 += __shfl_xor(p2, 8, 16); p3 += __shfl_xor(p3, 8, 16);
            const float ee0 = __expf(p0), ee1 = __expf(p1);
            const float ee2 = __expf(p2), ee3 = __expf(p3);
            acc += ee0 * x0 + ee1 * x1 + ee2 * x2 + ee3 * x3;
            den += ee0 + ee1 + ee2 + ee3;
        }
        for (; k < deg; ++k) {
            const int s = csr_src[base + k];
            const float4 ea = csr_ea[base + k];
            const float xv = bf2f(xl[(size_t)s * HC + j]);
            float mm = xv + xrd + ea.x * w0 + ea.y * w1 + ea.z * w2 + ea.w * w3;
            mm = (mm > 0.f) ? mm : NEG * mm;
            const float ee = __expf(head_sum(mm * aj));
            acc += ee * xv;
            den += ee;
        }
        gv = acc / den + gbs[j];
        g[(size_t)d * HC + j] = gv;
    }
    // block-partial LN1 stats + last-block reduction
    float s = gv, ss = gv * gv;
    for (int m = 32; m >= 1; m >>= 1) { s += __shfl_xor(s, m); ss += __shfl_xor(ss, m); }
    __shared__ float sr[4], ssr[4];
    const int w = t >> 6;
    if ((t & 63) == 0) { sr[w] = s; ssr[w] = ss; }
    __syncthreads();
    if (t == 0) {
        part[blockIdx.x] = make_float2(sr[0] + sr[1] + sr[2] + sr[3],
                                       ssr[0] + ssr[1] + ssr[2] + ssr[3]);
        __threadfence();
        amLast = (atomicAdd(ctr, 1u) == (unsigned)gridDim.x - 1u);
    }
    __syncthreads();
    if (amLast) {
        __threadfence();
        double ds = 0.0, dss = 0.0;
        const volatile float* vp = (const volatile float*)part;
        for (int i = t; i < (int)gridDim.x; i += 256) {
            ds  += (double)vp[2 * i];
            dss += (double)vp[2 * i + 1];
        }
        for (int m = 32; m >= 1; m >>= 1) { ds += __shfl_xor(ds, m); dss += __shfl_xor(dss, m); }
        __shared__ double dsr[4], dssr[4];
        if ((t & 63) == 0) { dsr[w] = ds; dssr[w] = dss; }
        __syncthreads();
        if (t == 0) {
            stats[0] = dsr[0] + dsr[1] + dsr[2] + dsr[3];
            stats[1] = dssr[0] + dssr[1] + dssr[2] + dssr[3];
        }
    }
}

// ---- apply LN1 + relu + linear(32->16); last block reduces LN2 stats ---------
__global__ __launch_bounds__(256) void k_mid(
    const float* __restrict__ g,
    const float* __restrict__ n1w, const float* __restrict__ n1b,
    const float* __restrict__ linW, const float* __restrict__ linb,
    const double* __restrict__ stats1, float* __restrict__ g2,
    float2* __restrict__ part, unsigned* __restrict__ ctr,
    double* __restrict__ stats2)
{
    __shared__ float Ws[HC * NC];
    __shared__ float rs[16][HC + 1];
    __shared__ bool amLast;
    const int t = threadIdx.x;
    for (int i = t; i < HC * NC; i += 256) Ws[i] = linW[i];
    const double cnt = (double)N_NODES * HC;
    const double mud = stats1[0] / cnt;
    const float mu  = (float)mud;
    const float var = (float)(stats1[1] / cnt - mud * mud);
    const float inv = rsqrtf(var + EPS);
    const int n0 = blockIdx.x * 16;
    for (int i = t; i < 16 * HC; i += 256) {
        int r = i >> 5, j = i & 31;
        int n = n0 + r;
        float v = (n < N_NODES) ? g[(size_t)n * HC + j] : mu;
        v = (v - mu) * inv * n1w[j] + n1b[j];
        rs[r][j] = fmaxf(v, 0.f);
    }
    __syncthreads();
    const int r = t >> 4, c = t & 15;
    const int n = n0 + r;
    float acc = linb[c];
#pragma unroll
    for (int j = 0; j < HC; ++j) acc += rs[r][j] * Ws[j * NC + c];
    float val = (n < N_NODES) ? acc : 0.f;
    if (n < N_NODES) g2[(size_t)n * NC + c] = acc;
    float s = val, ss = val * val;
    for (int m = 32; m >= 1; m >>= 1) { s += __shfl_xor(s, m); ss += __shfl_xor(ss, m); }
    __shared__ float sr[4], ssr[4];
    const int w = t >> 6;
    if ((t & 63) == 0) { sr[w] = s; ssr[w] = ss; }
    __syncthreads();
    if (t == 0) {
        part[blockIdx.x] = make_float2(sr[0] + sr[1] + sr[2] + sr[3],
                                       ssr[0] + ssr[1] + ssr[2] + ssr[3]);
        __threadfence();
        amLast = (atomicAdd(ctr, 1u) == (unsigned)gridDim.x - 1u);
    }
    __syncthreads();
    if (amLast) {
        __threadfence();
        double ds = 0.0, dss = 0.0;
        const volatile float* vp = (const volatile float*)part;
        for (int i = t; i < (int)gridDim.x; i += 256) {
            ds  += (double)vp[2 * i];
            dss += (double)vp[2 * i + 1];
        }
        for (int m = 32; m >= 1; m >>= 1) { ds += __shfl_xor(ds, m); dss += __shfl_xor(dss, m); }
        __shared__ double dsr[4], dssr[4];
        if ((t & 63) == 0) { dsr[w] = ds; dssr[w] = dss; }
        __syncthreads();
        if (t == 0) {
            stats2[0] = dsr[0] + dsr[1] + dsr[2] + dsr[3];
            stats2[1] = dssr[0] + dssr[1] + dssr[2] + dssr[3];
        }
    }
}

// ---- fused: apply LN2 + residual + relu + jk-max, then next-layer transforms -
__global__ __launch_bounds__(256) void k_ftrans(
    const float* __restrict__ g2, const float* __restrict__ n2w,
    const float* __restrict__ n2b, const double* __restrict__ stats2,
    float* __restrict__ h, float* __restrict__ jk,
    const float* __restrict__ Wl, const float* __restrict__ bl,
    const float* __restrict__ Wr, const float* __restrict__ br,
    unsigned short* __restrict__ xl, unsigned short* __restrict__ xr)
{
    __shared__ float Wls[NC * HC], Wrs[NC * HC];
    __shared__ float hs[8][NC + 1];
    const int t = threadIdx.x;
    for (int i = t; i < NC * HC; i += 256) { Wls[i] = Wl[i]; Wrs[i] = Wr[i]; }
    const double cnt = (double)N_NODES * NC;
    const double mud = stats2[0] / cnt;
    const float mu  = (float)mud;
    const float var = (float)(stats2[1] / cnt - mud * mud);
    const float inv = rsqrtf(var + EPS);
    const int n0 = blockIdx.x * 8;
    if (t < 8 * NC) {
        int r = t >> 4, c = t & 15;
        int n = n0 + r;
        if (n < N_NODES) {
            size_t idx = (size_t)n * NC + c;
            float v = (g2[idx] - mu) * inv * n2w[c] + n2b[c];
            float hn = fmaxf(v + h[idx], 0.f);
            h[idx] = hn;
            jk[idx] = fmaxf(jk[idx], hn);
            hs[r][c] = hn;
        } else hs[r][c] = 0.f;
    }
    __syncthreads();
    const int r = t >> 5;
    const int j = t & 31;
    const int n = n0 + r;
    float al = bl[j], ar = br[j];
#pragma unroll
    for (int c = 0; c < NC; ++c) {
        float hv = hs[r][c];
        al += hv * Wls[c * HC + j];
        ar += hv * Wrs[c * HC + j];
    }
    if (n < N_NODES) {
        xl[(size_t)n * HC + j] = f2bf(al);
        xr[(size_t)n * HC + j] = f2bf(ar);
    }
}

// ---- last layer: apply LN2, residual + relu, update h and jk-max -------------
__global__ __launch_bounds__(256) void k_final(
    const float* __restrict__ g2, const float* __restrict__ n2w,
    const float* __restrict__ n2b, const double* __restrict__ stats2,
    float* __restrict__ h, float* __restrict__ jk)
{
    const int i = blockIdx.x * 256 + threadIdx.x;
    if (i >= N_NODES * NC) return;
    const double cnt = (double)N_NODES * NC;
    const double mud = stats2[0] / cnt;
    const float mu  = (float)mud;
    const float var = (float)(stats2[1] / cnt - mud * mud);
    const float inv = rsqrtf(var + EPS);
    const int c = i & (NC - 1);
    float v = (g2[i] - mu) * inv * n2w[c] + n2b[c];
    float hn = fmaxf(v + h[i], 0.f);
    h[i] = hn;
    jk[i] = fmaxf(jk[i], hn);
}

extern "C" void kernel_launch(void* const* d_in, const int* in_sizes, int n_in,
                              void* d_out, int out_size, void* d_ws, size_t ws_size,
                              hipStream_t stream)
{
    const float* x     = (const float*)d_in[0];
    const int*   eidx  = (const int*)d_in[1];
    const float* eattr = (const float*)d_in[2];
    const float* embW  = (const float*)d_in[3];
    const float* embB  = (const float*)d_in[4];
    const float* ln0w  = (const float*)d_in[5];
    const float* ln0b  = (const float*)d_in[6];
    const float* Wl    = (const float*)d_in[7];
    const float* bl    = (const float*)d_in[8];
    const float* Wr    = (const float*)d_in[9];
    const float* br    = (const float*)d_in[10];
    const float* We    = (const float*)d_in[11];
    const float* att   = (const float*)d_in[12];
    const float* gatb  = (const float*)d_in[13];
    const float* n1w   = (const float*)d_in[14];
    const float* n1b   = (const float*)d_in[15];
    const float* linW  = (const float*)d_in[16];
    const float* linb  = (const float*)d_in[17];
    const float* n2w   = (const float*)d_in[18];
    const float* n2b   = (const float*)d_in[19];
    float* out = (float*)d_out;

    // ---- workspace layout (with lifetime overlays) ----
    char* ws = (char*)d_ws;
    double* stats = (double*)ws;                 // [0..1]=LN1, [2..3]=LN2
    char* p = ws + 1024;
    int* bcnt = (int*)p;                         // 1 KB  (zeroed)
    unsigned* ctr = (unsigned*)(p + 1024);       // 1 KB  (zeroed): 0=bhist,1..4=agg/mid
    p += 2048;
    int* bbase = (int*)p; p += 4096;             // 257 ints
    int* bcur  = (int*)p; p += 1024;             // 256 ints
    int* offsets = (int*)p; p += (size_t)(N_NODES + 64) * 4;
    // union A: tmp_se (CSR build)  <->  g (per-layer), both 12.8 MB
    int2* tmp_se = (int2*)p;
    float* g     = (float*)p;
    p += (size_t)N_EDGES * 8;
    int* csr_src = (int*)p; p += (size_t)N_EDGES * 4;
    float4* csr_ea = (float4*)p; p += (size_t)N_EDGES * 16;
    // union B: tmp_ea (CSR build) <-> h/xl/xr/g2 (per-layer), both 25.6 MB
    float4* tmp_ea = (float4*)p;
    {
        char* q = p;
        p += (size_t)N_EDGES * 16;
        float* hq = (float*)q; q += (size_t)N_NODES * NC * 4;
        unsigned short* xlq = (unsigned short*)q; q += (size_t)N_NODES * HC * 2;
        unsigned short* xrq = (unsigned short*)q; q += (size_t)N_NODES * HC * 2;
        float* g2q = (float*)q;
        float2* part1 = (float2*)p; p += (size_t)AGG_BLKS * 8;
        float2* part2 = (float2*)p; p += (size_t)MID_BLKS * 8;

        const int* srcp = eidx;
        const int* dstp = eidx + N_EDGES;

        // CSR build: histogram(+fused scan), LDS bucket scatter w/ eattr relay,
        // per-bucket counting sort
        hipMemsetAsync(bcnt, 0, 2048, stream);
        k_bhist<<<P1_BLKS, 256, 0, stream>>>(dstp, bcnt, ctr, bbase, bcur);
        k_pass1<<<P1_BLKS, 256, 0, stream>>>(srcp, dstp, (const float4*)eattr,
                                             bcur, tmp_se, tmp_ea);
        k_pass2<<<NBUCK, 256, 0, stream>>>(bbase, tmp_se, tmp_ea,
                                           offsets, csr_src, csr_ea);

        k_embed<<<(N_NODES + 15) / 16, 256, 0, stream>>>(x, embW, embB, ln0w, ln0b, hq, out);

        // layer 0
        k_trans<<<(N_NODES + 7) / 8, 256, 0, stream>>>(
            hq, Wl, bl, Wr, br, xlq, xrq);
        k_agg<<<AGG_BLKS, 256, 0, stream>>>(
            offsets, csr_src, csr_ea, We, att, gatb, xlq, xrq, g, part1, ctr + 1, stats);
        k_mid<<<MID_BLKS, 256, 0, stream>>>(
            g, n1w, n1b, linW, linb, stats, g2q, part2, ctr + 2, stats + 2);
        // final(0) fused with trans(1)
        k_ftrans<<<(N_NODES + 7) / 8, 256, 0, stream>>>(
            g2q, n2w, n2b, stats + 2, hq, out,
            Wl + NC * HC, bl + HC, Wr + NC * HC, br + HC, xlq, xrq);
        // layer 1
        k_agg<<<AGG_BLKS, 256, 0, stream>>>(
            offsets, csr_src, csr_ea, We + NED * HC, att + HC, gatb + HC,
            xlq, xrq, g, part1, ctr + 3, stats);
        k_mid<<<MID_BLKS, 256, 0, stream>>>(
            g, n1w + HC, n1b + HC, linW + HC * NC, linb + NC, stats, g2q,
            part2, ctr + 4, stats + 2);
        k_final<<<(N_NODES * NC + 255) / 256, 256, 0, stream>>>(
            g2q, n2w + NC, n2b + NC, stats + 2, hq, out);
    }
}

// Round 8
// 517.549 us; speedup vs baseline: 2.8306x; 2.8306x over previous
//
#include <hip/hip_runtime.h>

#define N_NODES 100000
#define N_EDGES 1600000
#define NF 128
#define NC 16
#define NH 2
#define HC 32   // NH*NC
#define NL 2
#define NED 4
#define EPS 1e-5f
#define NEG 0.2f
#define NBUCK 196                    // ceil(N_NODES / 512)
#define P1_CHUNK 4096
#define P1_BLKS ((N_EDGES + P1_CHUNK - 1) / P1_CHUNK)   // 391
#define AGG_BLKS ((N_NODES + 7) / 8)               // 12500
#define MID_BLKS ((N_NODES + 15) / 16)             // 6250

// ---- bf16 helpers (manual, RTN-even) -----------------------------------------
__device__ __forceinline__ unsigned short f2bf(float f) {
    unsigned int u = __float_as_uint(f);
    u += 0x7fffu + ((u >> 16) & 1u);
    return (unsigned short)(u >> 16);
}
__device__ __forceinline__ float bf2f(unsigned short u) {
    return __uint_as_float(((unsigned int)u) << 16);
}

// ---------------- embed: h = relu(node_LN(x @ W + b)) ; jk = h ----------------
__global__ __launch_bounds__(256) void k_embed(
    const float* __restrict__ x, const float* __restrict__ W,
    const float* __restrict__ b, const float* __restrict__ lnw,
    const float* __restrict__ lnb, float* __restrict__ h, float* __restrict__ jk)
{
    __shared__ float Ws[NF * NC];
    __shared__ float xs[16][NF + 4];
    const int t = threadIdx.x;
    for (int i = t; i < NF * NC; i += 256) Ws[i] = W[i];
    const int n0 = blockIdx.x * 16;
    for (int i = t; i < 16 * NF; i += 256) {
        int r = i >> 7, f = i & (NF - 1);
        int n = n0 + r;
        xs[r][f] = (n < N_NODES) ? x[(size_t)n * NF + f] : 0.f;
    }
    __syncthreads();
    const int r = t >> 4;
    const int c = t & 15;
    const int n = n0 + r;
    float acc = b[c];
#pragma unroll 16
    for (int f = 0; f < NF; ++f) acc += xs[r][f] * Ws[f * NC + c];
    float s = acc;
    for (int m = 8; m >= 1; m >>= 1) s += __shfl_xor(s, m, 16);
    float mu = s * (1.f / 16.f);
    float d = acc - mu;
    float v = d * d;
    for (int m = 8; m >= 1; m >>= 1) v += __shfl_xor(v, m, 16);
    float inv = rsqrtf(v * (1.f / 16.f) + EPS);
    float out = fmaxf(d * inv * lnw[c] + lnb[c], 0.f);
    if (n < N_NODES) {
        h[(size_t)n * NC + c]  = out;
        jk[(size_t)n * NC + c] = out;
    }
}

// ---- bucket histogram (bucket = dst >> 9), LDS-staged (NO fences) ------------
__global__ __launch_bounds__(256) void k_bhist(
    const int* __restrict__ dst, int* __restrict__ bcnt)
{
    __shared__ int hist[256];
    const int t = threadIdx.x;
    hist[t] = 0;
    __syncthreads();
    const int e0 = blockIdx.x * P1_CHUNK;
    const int cnt = min(P1_CHUNK, N_EDGES - e0);
    for (int i = t; i < cnt; i += 256)
        atomicAdd(&hist[dst[e0 + i] >> 9], 1);
    __syncthreads();
    if (hist[t] > 0) atomicAdd(&bcnt[t], hist[t]);
}

// ---- scan 196 bucket counts -> bases + working cursors -----------------------
__global__ __launch_bounds__(256) void k_bscan(
    const int* __restrict__ bcnt, int* __restrict__ bbase, int* __restrict__ bcur)
{
    __shared__ int tmp[256];
    const int t = threadIdx.x;
    int v0 = bcnt[t];
    tmp[t] = v0;
    __syncthreads();
    for (int off = 1; off < 256; off <<= 1) {
        int v = (t >= off) ? tmp[t - off] : 0;
        __syncthreads();
        tmp[t] += v;
        __syncthreads();
    }
    int excl = tmp[t] - v0;
    bbase[t] = excl;
    bcur[t]  = excl;
    if (t == 255) bbase[256] = tmp[t];   // == N_EDGES
}

// ---- pass1: LDS-staged bucket scatter; relays eattr (chunk-local gather) -----
// staged payload: {src, (e<<9)|dst_local}; e < 2^21, dst_local < 512
__global__ __launch_bounds__(256) void k_pass1(
    const int* __restrict__ src, const int* __restrict__ dst,
    const float4* __restrict__ ea4, int* __restrict__ bcur,
    int2* __restrict__ tmp_se, float4* __restrict__ tmp_ea)
{
    __shared__ int2 stage[P1_CHUNK];                 // 32 KB
    __shared__ unsigned char bstage[P1_CHUNK];       // 4 KB
    __shared__ int hist[256];
    __shared__ int exc[256];
    __shared__ int gbase[256];
    __shared__ int scanbuf[256];
    const int t = threadIdx.x;
    const int e0 = blockIdx.x * P1_CHUNK;
    const int cnt = min(P1_CHUNK, N_EDGES - e0);
    hist[t] = 0;
    __syncthreads();
    int mys[16], myb[16], myp[16];
    int nv = 0;
#pragma unroll
    for (int k = 0; k < 16; ++k) {
        int i = k * 256 + t;
        if (i < cnt) {
            int e = e0 + i;
            int d = dst[e];
            mys[nv] = src[e];
            myb[nv] = d >> 9;
            myp[nv] = (e << 9) | (d & 511);
            atomicAdd(&hist[d >> 9], 1);
            ++nv;
        }
    }
    __syncthreads();
    int hv = hist[t];
    scanbuf[t] = hv;
    __syncthreads();
    for (int off = 1; off < 256; off <<= 1) {
        int v = (t >= off) ? scanbuf[t - off] : 0;
        __syncthreads();
        scanbuf[t] += v;
        __syncthreads();
    }
    int ex = scanbuf[t] - hv;
    hist[t] = ex;            // becomes local cursor
    exc[t]  = ex;
    __syncthreads();
    for (int k = 0; k < nv; ++k) {
        int pos = atomicAdd(&hist[myb[k]], 1);
        stage[pos]  = make_int2(mys[k], myp[k]);
        bstage[pos] = (unsigned char)myb[k];
    }
    __syncthreads();
    {
        int c = hist[t] - exc[t];
        gbase[t] = (c > 0) ? atomicAdd(&bcur[t], c) : 0;
    }
    __syncthreads();
    // flush: bucket runs -> contiguous global slots; ea4 gather stays in the
    // chunk's 64 KB window (L2-resident streaming)
    for (int i = t; i < cnt; i += 256) {
        int b = bstage[i];
        int2 se = stage[i];
        int e = (int)(((unsigned int)se.y) >> 9);
        int gpos = gbase[b] + (i - exc[b]);
        tmp_se[gpos] = se;
        tmp_ea[gpos] = ea4[e];
    }
}

// ---- pass2: one block per bucket; per-dst LDS hist+scan -> offsets + CSR -----
__global__ __launch_bounds__(256) void k_pass2(
    const int* __restrict__ bbase, const int2* __restrict__ tmp_se,
    const float4* __restrict__ tmp_ea,
    int* __restrict__ offsets, int* __restrict__ csr_src, float4* __restrict__ csr_ea)
{
    __shared__ int hist[512];
    __shared__ int cur[512];
    __shared__ int scanbuf[256];
    const int b = blockIdx.x, t = threadIdx.x;
    const int ebeg = bbase[b], eend = bbase[b + 1];
    hist[t] = 0; hist[t + 256] = 0;
    __syncthreads();
    for (int i = ebeg + t; i < eend; i += 256)
        atomicAdd(&hist[tmp_se[i].y & 511], 1);
    __syncthreads();
    int a0 = hist[2 * t], a1 = hist[2 * t + 1];
    int pair = a0 + a1;
    scanbuf[t] = pair;
    __syncthreads();
    for (int off = 1; off < 256; off <<= 1) {
        int v = (t >= off) ? scanbuf[t - off] : 0;
        __syncthreads();
        scanbuf[t] += v;
        __syncthreads();
    }
    int ex2 = scanbuf[t] - pair;
    cur[2 * t]     = ex2;
    cur[2 * t + 1] = ex2 + a0;
    __syncthreads();
    const int n0 = b * 512;
#pragma unroll
    for (int k = 0; k < 2; ++k) {
        int i = t + k * 256;
        int n = n0 + i;
        if (n < N_NODES) offsets[n] = ebeg + cur[i];
    }
    if (b == NBUCK - 1 && t == 0) offsets[N_NODES] = N_EDGES;
    __syncthreads();
    // permute (writes stay inside this bucket's L2-resident window)
    for (int i = ebeg + t; i < eend; i += 256) {
        int2 se = tmp_se[i];
        float4 ea = tmp_ea[i];
        int dl = se.y & 511;
        int pos = ebeg + atomicAdd(&cur[dl], 1);
        csr_src[pos] = se.x;
        csr_ea[pos]  = ea;
    }
}

// ---- per-layer: xl/xr transforms (bf16 out) ----------------------------------
__global__ __launch_bounds__(256) void k_trans(
    const float* __restrict__ h, const float* __restrict__ Wl, const float* __restrict__ bl,
    const float* __restrict__ Wr, const float* __restrict__ br,
    unsigned short* __restrict__ xl, unsigned short* __restrict__ xr)
{
    __shared__ float Wls[NC * HC], Wrs[NC * HC];
    __shared__ float hs[8][NC + 1];
    const int t = threadIdx.x;
    for (int i = t; i < NC * HC; i += 256) { Wls[i] = Wl[i]; Wrs[i] = Wr[i]; }
    const int n0 = blockIdx.x * 8;
    for (int i = t; i < 8 * NC; i += 256) {
        int r = i >> 4, c = i & 15;
        int n = n0 + r;
        hs[r][c] = (n < N_NODES) ? h[(size_t)n * NC + c] : 0.f;
    }
    __syncthreads();
    const int r = t >> 5;
    const int j = t & 31;
    const int n = n0 + r;
    float al = bl[j], ar = br[j];
#pragma unroll
    for (int c = 0; c < NC; ++c) {
        float hv = hs[r][c];
        al += hv * Wls[c * HC + j];
        ar += hv * Wrs[c * HC + j];
    }
    if (n < N_NODES) {
        xl[(size_t)n * HC + j] = f2bf(al);
        xr[(size_t)n * HC + j] = f2bf(ar);
    }
}

__device__ __forceinline__ float head_sum(float p) {
    p += __shfl_xor(p, 1, 16);
    p += __shfl_xor(p, 2, 16);
    p += __shfl_xor(p, 4, 16);
    p += __shfl_xor(p, 8, 16);
    return p;
}

// ---- aggregation: sequential CSR reads, unroll-4; partial stats (NO fences) --
__global__ __launch_bounds__(256) void k_agg(
    const int* __restrict__ offsets, const int* __restrict__ csr_src,
    const float4* __restrict__ csr_ea,
    const float* __restrict__ We, const float* __restrict__ att,
    const float* __restrict__ gat_b,
    const unsigned short* __restrict__ xl, const unsigned short* __restrict__ xr,
    float* __restrict__ g, float2* __restrict__ part)
{
    __shared__ float Wes[NED * HC];
    __shared__ float atts[HC], gbs[HC];
    const int t = threadIdx.x;
    if (t < NED * HC) Wes[t] = We[t];
    if (t < HC) { atts[t] = att[t]; gbs[t] = gat_b[t]; }
    __syncthreads();
    const int grp = t >> 5;
    const int j   = t & 31;
    const int d = blockIdx.x * 8 + grp;
    float gv = 0.f;
    if (d < N_NODES) {
        const float aj = atts[j];
        const float w0 = Wes[j], w1 = Wes[HC + j], w2 = Wes[2 * HC + j], w3 = Wes[3 * HC + j];
        const float xld = bf2f(xl[(size_t)d * HC + j]);
        const float xrd = bf2f(xr[(size_t)d * HC + j]);
        // self-loop (ew = 0); logits tiny: exp without segment-max is exact enough
        float m = xld + xrd;
        m = (m > 0.f) ? m : NEG * m;
        float eh = __expf(head_sum(m * aj));
        float acc = eh * xld;
        float den = eh;
        const int base = offsets[d];
        const int deg  = offsets[d + 1] - base;
        int k = 0;
        for (; k + 4 <= deg; k += 4) {
            const int b0 = base + k;
            const int s0 = csr_src[b0],     s1 = csr_src[b0 + 1];
            const int s2 = csr_src[b0 + 2], s3 = csr_src[b0 + 3];
            const float4 e0 = csr_ea[b0],     e1 = csr_ea[b0 + 1];
            const float4 e2 = csr_ea[b0 + 2], e3 = csr_ea[b0 + 3];
            const float x0 = bf2f(xl[(size_t)s0 * HC + j]);
            const float x1 = bf2f(xl[(size_t)s1 * HC + j]);
            const float x2 = bf2f(xl[(size_t)s2 * HC + j]);
            const float x3 = bf2f(xl[(size_t)s3 * HC + j]);
            float m0 = x0 + xrd + e0.x * w0 + e0.y * w1 + e0.z * w2 + e0.w * w3;
            float m1 = x1 + xrd + e1.x * w0 + e1.y * w1 + e1.z * w2 + e1.w * w3;
            float m2 = x2 + xrd + e2.x * w0 + e2.y * w1 + e2.z * w2 + e2.w * w3;
            float m3 = x3 + xrd + e3.x * w0 + e3.y * w1 + e3.z * w2 + e3.w * w3;
            m0 = (m0 > 0.f) ? m0 : NEG * m0;
            m1 = (m1 > 0.f) ? m1 : NEG * m1;
            m2 = (m2 > 0.f) ? m2 : NEG * m2;
            m3 = (m3 > 0.f) ? m3 : NEG * m3;
            float p0 = m0 * aj, p1 = m1 * aj, p2 = m2 * aj, p3 = m3 * aj;
            p0 += __shfl_xor(p0, 1, 16); p1 += __shfl_xor(p1, 1, 16);
            p2 += __shfl_xor(p2, 1, 16); p3 += __shfl_xor(p3, 1, 16);
            p0 += __shfl_xor(p0, 2, 16); p1 += __shfl_xor(p1, 2, 16);
            p2 += __shfl_xor(p2, 2, 16); p3 += __shfl_xor(p3, 2, 16);
            p0 += __shfl_xor(p0, 4, 16); p1 += __shfl_xor(p1, 4, 16);
            p2 += __shfl_xor(p2, 4, 16); p3 += __shfl_xor(p3, 4, 16);
            p0 += __shfl_xor(p0, 8, 16); p1 += __shfl_xor(p1, 8, 16);
            p2 += __shfl_xor(p2, 8, 16); p3 += __shfl_xor(p3, 8, 16);
            const float ee0 = __expf(p0), ee1 = __expf(p1);
            const float ee2 = __expf(p2), ee3 = __expf(p3);
            acc += ee0 * x0 + ee1 * x1 + ee2 * x2 + ee3 * x3;
            den += ee0 + ee1 + ee2 + ee3;
        }
        for (; k < deg; ++k) {
            const int s = csr_src[base + k];
            const float4 ea = csr_ea[base + k];
            const float xv = bf2f(xl[(size_t)s * HC + j]);
            float mm = xv + xrd + ea.x * w0 + ea.y * w1 + ea.z * w2 + ea.w * w3;
            mm = (mm > 0.f) ? mm : NEG * mm;
            const float ee = __expf(head_sum(mm * aj));
            acc += ee * xv;
            den += ee;
        }
        gv = acc / den + gbs[j];
        g[(size_t)d * HC + j] = gv;
    }
    float s = gv, ss = gv * gv;
    for (int m = 32; m >= 1; m >>= 1) { s += __shfl_xor(s, m); ss += __shfl_xor(ss, m); }
    __shared__ float sr[4], ssr[4];
    const int w = t >> 6;
    if ((t & 63) == 0) { sr[w] = s; ssr[w] = ss; }
    __syncthreads();
    if (t == 0) part[blockIdx.x] = make_float2(sr[0] + sr[1] + sr[2] + sr[3],
                                               ssr[0] + ssr[1] + ssr[2] + ssr[3]);
}

// ---- reduce block partials -> stats[0..1] ------------------------------------
__global__ __launch_bounds__(256) void k_red(
    const float2* __restrict__ part, int n, double* __restrict__ out)
{
    const int t = threadIdx.x;
    double s = 0.0, ss = 0.0;
    for (int i = t; i < n; i += 256) {
        float2 p = part[i];
        s += (double)p.x; ss += (double)p.y;
    }
    for (int m = 32; m >= 1; m >>= 1) { s += __shfl_xor(s, m); ss += __shfl_xor(ss, m); }
    __shared__ double sr[4], ssr[4];
    const int w = t >> 6;
    if ((t & 63) == 0) { sr[w] = s; ssr[w] = ss; }
    __syncthreads();
    if (t == 0) {
        out[0] = sr[0] + sr[1] + sr[2] + sr[3];
        out[1] = ssr[0] + ssr[1] + ssr[2] + ssr[3];
    }
}

// ---- apply LN1 + relu + linear(32->16) + partial stats for LN2 ---------------
__global__ __launch_bounds__(256) void k_mid(
    const float* __restrict__ g,
    const float* __restrict__ n1w, const float* __restrict__ n1b,
    const float* __restrict__ linW, const float* __restrict__ linb,
    const double* __restrict__ stats1, float* __restrict__ g2,
    float2* __restrict__ part)
{
    __shared__ float Ws[HC * NC];
    __shared__ float rs[16][HC + 1];
    const int t = threadIdx.x;
    for (int i = t; i < HC * NC; i += 256) Ws[i] = linW[i];
    const double cnt = (double)N_NODES * HC;
    const double mud = stats1[0] / cnt;
    const float mu  = (float)mud;
    const float var = (float)(stats1[1] / cnt - mud * mud);
    const float inv = rsqrtf(var + EPS);
    const int n0 = blockIdx.x * 16;
    for (int i = t; i < 16 * HC; i += 256) {
        int r = i >> 5, j = i & 31;
        int n = n0 + r;
        float v = (n < N_NODES) ? g[(size_t)n * HC + j] : mu;
        v = (v - mu) * inv * n1w[j] + n1b[j];
        rs[r][j] = fmaxf(v, 0.f);
    }
    __syncthreads();
    const int r = t >> 4, c = t & 15;
    const int n = n0 + r;
    float acc = linb[c];
#pragma unroll
    for (int j = 0; j < HC; ++j) acc += rs[r][j] * Ws[j * NC + c];
    float val = (n < N_NODES) ? acc : 0.f;
    if (n < N_NODES) g2[(size_t)n * NC + c] = acc;
    float s = val, ss = val * val;
    for (int m = 32; m >= 1; m >>= 1) { s += __shfl_xor(s, m); ss += __shfl_xor(ss, m); }
    __shared__ float sr[4], ssr[4];
    const int w = t >> 6;
    if ((t & 63) == 0) { sr[w] = s; ssr[w] = ss; }
    __syncthreads();
    if (t == 0) part[blockIdx.x] = make_float2(sr[0] + sr[1] + sr[2] + sr[3],
                                               ssr[0] + ssr[1] + ssr[2] + ssr[3]);
}

// ---- fused: apply LN2 + residual + relu + jk-max, then next-layer transforms -
__global__ __launch_bounds__(256) void k_ftrans(
    const float* __restrict__ g2, const float* __restrict__ n2w,
    const float* __restrict__ n2b, const double* __restrict__ stats2,
    float* __restrict__ h, float* __restrict__ jk,
    const float* __restrict__ Wl, const float* __restrict__ bl,
    const float* __restrict__ Wr, const float* __restrict__ br,
    unsigned short* __restrict__ xl, unsigned short* __restrict__ xr)
{
    __shared__ float Wls[NC * HC], Wrs[NC * HC];
    __shared__ float hs[8][NC + 1];
    const int t = threadIdx.x;
    for (int i = t; i < NC * HC; i += 256) { Wls[i] = Wl[i]; Wrs[i] = Wr[i]; }
    const double cnt = (double)N_NODES * NC;
    const double mud = stats2[0] / cnt;
    const float mu  = (float)mud;
    const float var = (float)(stats2[1] / cnt - mud * mud);
    const float inv = rsqrtf(var + EPS);
    const int n0 = blockIdx.x * 8;
    if (t < 8 * NC) {
        int r = t >> 4, c = t & 15;
        int n = n0 + r;
        if (n < N_NODES) {
            size_t idx = (size_t)n * NC + c;
            float v = (g2[idx] - mu) * inv * n2w[c] + n2b[c];
            float hn = fmaxf(v + h[idx], 0.f);
            h[idx] = hn;
            jk[idx] = fmaxf(jk[idx], hn);
            hs[r][c] = hn;
        } else hs[r][c] = 0.f;
    }
    __syncthreads();
    const int r = t >> 5;
    const int j = t & 31;
    const int n = n0 + r;
    float al = bl[j], ar = br[j];
#pragma unroll
    for (int c = 0; c < NC; ++c) {
        float hv = hs[r][c];
        al += hv * Wls[c * HC + j];
        ar += hv * Wrs[c * HC + j];
    }
    if (n < N_NODES) {
        xl[(size_t)n * HC + j] = f2bf(al);
        xr[(size_t)n * HC + j] = f2bf(ar);
    }
}

// ---- last layer: apply LN2, residual + relu, update h and jk-max -------------
__global__ __launch_bounds__(256) void k_final(
    const float* __restrict__ g2, const float* __restrict__ n2w,
    const float* __restrict__ n2b, const double* __restrict__ stats2,
    float* __restrict__ h, float* __restrict__ jk)
{
    const int i = blockIdx.x * 256 + threadIdx.x;
    if (i >= N_NODES * NC) return;
    const double cnt = (double)N_NODES * NC;
    const double mud = stats2[0] / cnt;
    const float mu  = (float)mud;
    const float var = (float)(stats2[1] / cnt - mud * mud);
    const float inv = rsqrtf(var + EPS);
    const int c = i & (NC - 1);
    float v = (g2[i] - mu) * inv * n2w[c] + n2b[c];
    float hn = fmaxf(v + h[i], 0.f);
    h[i] = hn;
    jk[i] = fmaxf(jk[i], hn);
}

extern "C" void kernel_launch(void* const* d_in, const int* in_sizes, int n_in,
                              void* d_out, int out_size, void* d_ws, size_t ws_size,
                              hipStream_t stream)
{
    const float* x     = (const float*)d_in[0];
    const int*   eidx  = (const int*)d_in[1];
    const float* eattr = (const float*)d_in[2];
    const float* embW  = (const float*)d_in[3];
    const float* embB  = (const float*)d_in[4];
    const float* ln0w  = (const float*)d_in[5];
    const float* ln0b  = (const float*)d_in[6];
    const float* Wl    = (const float*)d_in[7];
    const float* bl    = (const float*)d_in[8];
    const float* Wr    = (const float*)d_in[9];
    const float* br    = (const float*)d_in[10];
    const float* We    = (const float*)d_in[11];
    const float* att   = (const float*)d_in[12];
    const float* gatb  = (const float*)d_in[13];
    const float* n1w   = (const float*)d_in[14];
    const float* n1b   = (const float*)d_in[15];
    const float* linW  = (const float*)d_in[16];
    const float* linb  = (const float*)d_in[17];
    const float* n2w   = (const float*)d_in[18];
    const float* n2b   = (const float*)d_in[19];
    float* out = (float*)d_out;

    // ---- workspace layout (with lifetime overlays) ----
    char* ws = (char*)d_ws;
    double* stats = (double*)ws;                 // [0..1]=LN1, [2..3]=LN2
    char* p = ws + 1024;
    int* bcnt = (int*)p; p += 1024;              // 256 ints (zeroed)
    int* bbase = (int*)p; p += 4096;             // 257 ints
    int* bcur  = (int*)p; p += 1024;             // 256 ints
    int* offsets = (int*)p; p += (size_t)(N_NODES + 64) * 4;
    // union A: tmp_se (CSR build)  <->  g (per-layer), both 12.8 MB
    int2* tmp_se = (int2*)p;
    float* g     = (float*)p;
    p += (size_t)N_EDGES * 8;
    int* csr_src = (int*)p; p += (size_t)N_EDGES * 4;
    float4* csr_ea = (float4*)p; p += (size_t)N_EDGES * 16;
    // union B: tmp_ea (CSR build) <-> h/xl/xr/g2 (per-layer), both 25.6 MB
    float4* tmp_ea = (float4*)p;
    char* q = p;
    p += (size_t)N_EDGES * 16;
    float* hq = (float*)q; q += (size_t)N_NODES * NC * 4;
    unsigned short* xlq = (unsigned short*)q; q += (size_t)N_NODES * HC * 2;
    unsigned short* xrq = (unsigned short*)q; q += (size_t)N_NODES * HC * 2;
    float* g2q = (float*)q;
    float2* part1 = (float2*)p; p += (size_t)AGG_BLKS * 8;
    float2* part2 = (float2*)p; p += (size_t)MID_BLKS * 8;

    const int* srcp = eidx;
    const int* dstp = eidx + N_EDGES;

    // CSR build: bucket sort (LDS-staged, eattr relay) + per-bucket counting sort
    hipMemsetAsync(bcnt, 0, 1024, stream);
    k_bhist<<<P1_BLKS, 256, 0, stream>>>(dstp, bcnt);
    k_bscan<<<1, 256, 0, stream>>>(bcnt, bbase, bcur);
    k_pass1<<<P1_BLKS, 256, 0, stream>>>(srcp, dstp, (const float4*)eattr,
                                         bcur, tmp_se, tmp_ea);
    k_pass2<<<NBUCK, 256, 0, stream>>>(bbase, tmp_se, tmp_ea,
                                       offsets, csr_src, csr_ea);

    k_embed<<<(N_NODES + 15) / 16, 256, 0, stream>>>(x, embW, embB, ln0w, ln0b, hq, out);

    // layer 0
    k_trans<<<(N_NODES + 7) / 8, 256, 0, stream>>>(hq, Wl, bl, Wr, br, xlq, xrq);
    k_agg<<<AGG_BLKS, 256, 0, stream>>>(
        offsets, csr_src, csr_ea, We, att, gatb, xlq, xrq, g, part1);
    k_red<<<1, 256, 0, stream>>>(part1, AGG_BLKS, stats);
    k_mid<<<MID_BLKS, 256, 0, stream>>>(
        g, n1w, n1b, linW, linb, stats, g2q, part2);
    k_red<<<1, 256, 0, stream>>>(part2, MID_BLKS, stats + 2);
    k_ftrans<<<(N_NODES + 7) / 8, 256, 0, stream>>>(
        g2q, n2w, n2b, stats + 2, hq, out,
        Wl + NC * HC, bl + HC, Wr + NC * HC, br + HC, xlq, xrq);
    // layer 1
    k_agg<<<AGG_BLKS, 256, 0, stream>>>(
        offsets, csr_src, csr_ea, We + NED * HC, att + HC, gatb + HC,
        xlq, xrq, g, part1);
    k_red<<<1, 256, 0, stream>>>(part1, AGG_BLKS, stats);
    k_mid<<<MID_BLKS, 256, 0, stream>>>(
        g, n1w + HC, n1b + HC, linW + HC * NC, linb + NC, stats, g2q, part2);
    k_red<<<1, 256, 0, stream>>>(part2, MID_BLKS, stats + 2);
    k_final<<<(N_NODES * NC + 255) / 256, 256, 0, stream>>>(
        g2q, n2w + NC, n2b + NC, stats + 2, hq, out);
}

// Round 10
// 493.731 us; speedup vs baseline: 2.9671x; 1.0482x over previous
//
#include <hip/hip_runtime.h>

#define N_NODES 100000
#define N_EDGES 1600000
#define NF 128
#define NC 16
#define NH 2
#define HC 32   // NH*NC
#define NL 2
#define NED 4
#define EPS 1e-5f
#define NEG 0.2f
#define NBUCK 196                    // ceil(N_NODES / 512)
#define P1_CHUNK 4096
#define P1_BLKS ((N_EDGES + P1_CHUNK - 1) / P1_CHUNK)   // 391
#define AGG_BLKS ((N_NODES + 7) / 8)               // 12500
#define MID_BLKS ((N_NODES + 15) / 16)             // 6250

// ---- bf16 helpers (manual, RTN-even) -----------------------------------------
__device__ __forceinline__ unsigned short f2bf(float f) {
    unsigned int u = __float_as_uint(f);
    u += 0x7fffu + ((u >> 16) & 1u);
    return (unsigned short)(u >> 16);
}
__device__ __forceinline__ float bf2f(unsigned short u) {
    return __uint_as_float(((unsigned int)u) << 16);
}
__device__ __forceinline__ unsigned int pack_bf2(float a, float b) {
    return (unsigned int)f2bf(a) | ((unsigned int)f2bf(b) << 16);
}
__device__ __forceinline__ float bflo(int u) {
    return __uint_as_float(((unsigned int)u) << 16);
}
__device__ __forceinline__ float bfhi(int u) {
    return __uint_as_float(((unsigned int)u) & 0xffff0000u);
}

// ---------------- embed: h = relu(node_LN(x @ W + b)) ; jk = h ----------------
__global__ __launch_bounds__(256) void k_embed(
    const float* __restrict__ x, const float* __restrict__ W,
    const float* __restrict__ b, const float* __restrict__ lnw,
    const float* __restrict__ lnb, float* __restrict__ h, float* __restrict__ jk)
{
    __shared__ float Ws[NF * NC];
    __shared__ float xs[16][NF + 4];
    const int t = threadIdx.x;
    for (int i = t; i < NF * NC; i += 256) Ws[i] = W[i];
    const int n0 = blockIdx.x * 16;
    for (int i = t; i < 16 * NF; i += 256) {
        int r = i >> 7, f = i & (NF - 1);
        int n = n0 + r;
        xs[r][f] = (n < N_NODES) ? x[(size_t)n * NF + f] : 0.f;
    }
    __syncthreads();
    const int r = t >> 4;
    const int c = t & 15;
    const int n = n0 + r;
    float acc = b[c];
#pragma unroll 16
    for (int f = 0; f < NF; ++f) acc += xs[r][f] * Ws[f * NC + c];
    float s = acc;
    for (int m = 8; m >= 1; m >>= 1) s += __shfl_xor(s, m, 16);
    float mu = s * (1.f / 16.f);
    float d = acc - mu;
    float v = d * d;
    for (int m = 8; m >= 1; m >>= 1) v += __shfl_xor(v, m, 16);
    float inv = rsqrtf(v * (1.f / 16.f) + EPS);
    float out = fmaxf(d * inv * lnw[c] + lnb[c], 0.f);
    if (n < N_NODES) {
        h[(size_t)n * NC + c]  = out;
        jk[(size_t)n * NC + c] = out;
    }
}

// ---- bucket histogram (bucket = dst >> 9), LDS-staged ------------------------
__global__ __launch_bounds__(256) void k_bhist(
    const int* __restrict__ dst, int* __restrict__ bcnt)
{
    __shared__ int hist[256];
    const int t = threadIdx.x;
    hist[t] = 0;
    __syncthreads();
    const int e0 = blockIdx.x * P1_CHUNK;
    const int cnt = min(P1_CHUNK, N_EDGES - e0);
    for (int i = t; i < cnt; i += 256)
        atomicAdd(&hist[dst[e0 + i] >> 9], 1);
    __syncthreads();
    if (hist[t] > 0) atomicAdd(&bcnt[t], hist[t]);
}

// ---- scan 196 bucket counts -> bases + working cursors -----------------------
__global__ __launch_bounds__(256) void k_bscan(
    const int* __restrict__ bcnt, int* __restrict__ bbase, int* __restrict__ bcur)
{
    __shared__ int tmp[256];
    const int t = threadIdx.x;
    int v0 = bcnt[t];
    tmp[t] = v0;
    __syncthreads();
    for (int off = 1; off < 256; off <<= 1) {
        int v = (t >= off) ? tmp[t - off] : 0;
        __syncthreads();
        tmp[t] += v;
        __syncthreads();
    }
    int excl = tmp[t] - v0;
    bbase[t] = excl;
    bcur[t]  = excl;
    if (t == 255) bbase[256] = tmp[t];   // == N_EDGES
}

// ---- pass1: LDS-staged bucket scatter; packs {src, dl, bf16(ea)x4} -----------
// staged payload: {src, (e<<9)|dst_local}; e < 2^21, dst_local < 512
__global__ __launch_bounds__(256) void k_pass1(
    const int* __restrict__ src, const int* __restrict__ dst,
    const float4* __restrict__ ea4, int* __restrict__ bcur,
    int4* __restrict__ tmp_rec)
{
    __shared__ int2 stage[P1_CHUNK];                 // 32 KB
    __shared__ unsigned char bstage[P1_CHUNK];       // 4 KB
    __shared__ int hist[256];
    __shared__ int exc[256];
    __shared__ int gbase[256];
    __shared__ int scanbuf[256];
    const int t = threadIdx.x;
    const int e0 = blockIdx.x * P1_CHUNK;
    const int cnt = min(P1_CHUNK, N_EDGES - e0);
    hist[t] = 0;
    __syncthreads();
    int mys[16], myb[16], myp[16];
    int nv = 0;
#pragma unroll
    for (int k = 0; k < 16; ++k) {
        int i = k * 256 + t;
        if (i < cnt) {
            int e = e0 + i;
            int d = dst[e];
            mys[nv] = src[e];
            myb[nv] = d >> 9;
            myp[nv] = (e << 9) | (d & 511);
            atomicAdd(&hist[d >> 9], 1);
            ++nv;
        }
    }
    __syncthreads();
    int hv = hist[t];
    scanbuf[t] = hv;
    __syncthreads();
    for (int off = 1; off < 256; off <<= 1) {
        int v = (t >= off) ? scanbuf[t - off] : 0;
        __syncthreads();
        scanbuf[t] += v;
        __syncthreads();
    }
    int ex = scanbuf[t] - hv;
    hist[t] = ex;            // becomes local cursor
    exc[t]  = ex;
    __syncthreads();
    for (int k = 0; k < nv; ++k) {
        int pos = atomicAdd(&hist[myb[k]], 1);
        stage[pos]  = make_int2(mys[k], myp[k]);
        bstage[pos] = (unsigned char)myb[k];
    }
    __syncthreads();
    {
        int c = hist[t] - exc[t];
        gbase[t] = (c > 0) ? atomicAdd(&bcur[t], c) : 0;
    }
    __syncthreads();
    // flush: bucket runs -> contiguous slots; ea gather stays in chunk window
    for (int i = t; i < cnt; i += 256) {
        int b = bstage[i];
        int2 se = stage[i];
        int e  = (int)(((unsigned int)se.y) >> 9);
        int dl = se.y & 511;
        float4 ea = ea4[e];
        int gpos = gbase[b] + (i - exc[b]);
        tmp_rec[gpos] = make_int4(se.x, dl,
                                  (int)pack_bf2(ea.x, ea.y),
                                  (int)pack_bf2(ea.z, ea.w));
    }
}

// ---- pass2: one block per bucket; per-dst LDS hist+scan -> offsets + CSR -----
__global__ __launch_bounds__(256) void k_pass2(
    const int* __restrict__ bbase, const int4* __restrict__ tmp_rec,
    int* __restrict__ offsets, int4* __restrict__ csr)
{
    __shared__ int hist[512];
    __shared__ int cur[512];
    __shared__ int scanbuf[256];
    const int b = blockIdx.x, t = threadIdx.x;
    const int ebeg = bbase[b], eend = bbase[b + 1];
    hist[t] = 0; hist[t + 256] = 0;
    __syncthreads();
    for (int i = ebeg + t; i < eend; i += 256)
        atomicAdd(&hist[tmp_rec[i].y], 1);
    __syncthreads();
    int a0 = hist[2 * t], a1 = hist[2 * t + 1];
    int pair = a0 + a1;
    scanbuf[t] = pair;
    __syncthreads();
    for (int off = 1; off < 256; off <<= 1) {
        int v = (t >= off) ? scanbuf[t - off] : 0;
        __syncthreads();
        scanbuf[t] += v;
        __syncthreads();
    }
    int ex2 = scanbuf[t] - pair;
    cur[2 * t]     = ex2;
    cur[2 * t + 1] = ex2 + a0;
    __syncthreads();
    const int n0 = b * 512;
#pragma unroll
    for (int k = 0; k < 2; ++k) {
        int i = t + k * 256;
        int n = n0 + i;
        if (n < N_NODES) offsets[n] = ebeg + cur[i];
    }
    if (b == NBUCK - 1 && t == 0) offsets[N_NODES] = N_EDGES;
    __syncthreads();
    // permute (writes stay inside this bucket's L2-resident window)
    for (int i = ebeg + t; i < eend; i += 256) {
        int4 rec = tmp_rec[i];
        int pos = ebeg + atomicAdd(&cur[rec.y], 1);
        csr[pos] = rec;   // {src, dl(unused later), eab01, eab23}
    }
}

// ---- per-layer: xl/xr transforms (bf16 out) ----------------------------------
__global__ __launch_bounds__(256) void k_trans(
    const float* __restrict__ h, const float* __restrict__ Wl, const float* __restrict__ bl,
    const float* __restrict__ Wr, const float* __restrict__ br,
    unsigned short* __restrict__ xl, unsigned short* __restrict__ xr)
{
    __shared__ float Wls[NC * HC], Wrs[NC * HC];
    __shared__ float hs[8][NC + 1];
    const int t = threadIdx.x;
    for (int i = t; i < NC * HC; i += 256) { Wls[i] = Wl[i]; Wrs[i] = Wr[i]; }
    const int n0 = blockIdx.x * 8;
    for (int i = t; i < 8 * NC; i += 256) {
        int r = i >> 4, c = i & 15;
        int n = n0 + r;
        hs[r][c] = (n < N_NODES) ? h[(size_t)n * NC + c] : 0.f;
    }
    __syncthreads();
    const int r = t >> 5;
    const int j = t & 31;
    const int n = n0 + r;
    float al = bl[j], ar = br[j];
#pragma unroll
    for (int c = 0; c < NC; ++c) {
        float hv = hs[r][c];
        al += hv * Wls[c * HC + j];
        ar += hv * Wrs[c * HC + j];
    }
    if (n < N_NODES) {
        xl[(size_t)n * HC + j] = f2bf(al);
        xr[(size_t)n * HC + j] = f2bf(ar);
    }
}

__device__ __forceinline__ float head_sum(float p) {
    p += __shfl_xor(p, 1, 16);
    p += __shfl_xor(p, 2, 16);
    p += __shfl_xor(p, 4, 16);
    p += __shfl_xor(p, 8, 16);
    return p;
}

// ---- aggregation: single 16B record/edge, unroll-4; partial stats ------------
__global__ __launch_bounds__(256) void k_agg(
    const int* __restrict__ offsets, const int4* __restrict__ csr,
    const float* __restrict__ We, const float* __restrict__ att,
    const float* __restrict__ gat_b,
    const unsigned short* __restrict__ xl, const unsigned short* __restrict__ xr,
    float* __restrict__ g, float2* __restrict__ part)
{
    __shared__ float Wes[NED * HC];
    __shared__ float atts[HC], gbs[HC];
    const int t = threadIdx.x;
    if (t < NED * HC) Wes[t] = We[t];
    if (t < HC) { atts[t] = att[t]; gbs[t] = gat_b[t]; }
    __syncthreads();
    const int grp = t >> 5;
    const int j   = t & 31;
    const int d = blockIdx.x * 8 + grp;
    float gv = 0.f;
    if (d < N_NODES) {
        const float aj = atts[j];
        const float w0 = Wes[j], w1 = Wes[HC + j], w2 = Wes[2 * HC + j], w3 = Wes[3 * HC + j];
        const float xld = bf2f(xl[(size_t)d * HC + j]);
        const float xrd = bf2f(xr[(size_t)d * HC + j]);
        // self-loop (ew = 0); logits tiny: exp without segment-max is exact enough
        float m = xld + xrd;
        m = (m > 0.f) ? m : NEG * m;
        float eh = __expf(head_sum(m * aj));
        float acc = eh * xld;
        float den = eh;
        const int base = offsets[d];
        const int deg  = offsets[d + 1] - base;
        int k = 0;
        for (; k + 4 <= deg; k += 4) {
            const int b0 = base + k;
            const int4 r0 = csr[b0],     r1 = csr[b0 + 1];
            const int4 r2 = csr[b0 + 2], r3 = csr[b0 + 3];
            const float x0 = bf2f(xl[(size_t)r0.x * HC + j]);
            const float x1 = bf2f(xl[(size_t)r1.x * HC + j]);
            const float x2 = bf2f(xl[(size_t)r2.x * HC + j]);
            const float x3 = bf2f(xl[(size_t)r3.x * HC + j]);
            float m0 = x0 + xrd + bflo(r0.z) * w0 + bfhi(r0.z) * w1 + bflo(r0.w) * w2 + bfhi(r0.w) * w3;
            float m1 = x1 + xrd + bflo(r1.z) * w0 + bfhi(r1.z) * w1 + bflo(r1.w) * w2 + bfhi(r1.w) * w3;
            float m2 = x2 + xrd + bflo(r2.z) * w0 + bfhi(r2.z) * w1 + bflo(r2.w) * w2 + bfhi(r2.w) * w3;
            float m3 = x3 + xrd + bflo(r3.z) * w0 + bfhi(r3.z) * w1 + bflo(r3.w) * w2 + bfhi(r3.w) * w3;
            m0 = (m0 > 0.f) ? m0 : NEG * m0;
            m1 = (m1 > 0.f) ? m1 : NEG * m1;
            m2 = (m2 > 0.f) ? m2 : NEG * m2;
            m3 = (m3 > 0.f) ? m3 : NEG * m3;
            float p0 = m0 * aj, p1 = m1 * aj, p2 = m2 * aj, p3 = m3 * aj;
            p0 += __shfl_xor(p0, 1, 16); p1 += __shfl_xor(p1, 1, 16);
            p2 += __shfl_xor(p2, 1, 16); p3 += __shfl_xor(p3, 1, 16);
            p0 += __shfl_xor(p0, 2, 16); p1 += __shfl_xor(p1, 2, 16);
            p2 += __shfl_xor(p2, 2, 16); p3 += __shfl_xor(p3, 2, 16);
            p0 += __shfl_xor(p0, 4, 16); p1 += __shfl_xor(p1, 4, 16);
            p2 += __shfl_xor(p2, 4, 16); p3 += __shfl_xor(p3, 4, 16);
            p0 += __shfl_xor(p0, 8, 16); p1 += __shfl_xor(p1, 8, 16);
            p2 += __shfl_xor(p2, 8, 16); p3 += __shfl_xor(p3, 8, 16);
            const float ee0 = __expf(p0), ee1 = __expf(p1);
            const float ee2 = __expf(p2), ee3 = __expf(p3);
            acc += ee0 * x0 + ee1 * x1 + ee2 * x2 + ee3 * x3;
            den += ee0 + ee1 + ee2 + ee3;
        }
        for (; k < deg; ++k) {
            const int4 r = csr[base + k];
            const float xv = bf2f(xl[(size_t)r.x * HC + j]);
            float mm = xv + xrd + bflo(r.z) * w0 + bfhi(r.z) * w1 + bflo(r.w) * w2 + bfhi(r.w) * w3;
            mm = (mm > 0.f) ? mm : NEG * mm;
            const float ee = __expf(head_sum(mm * aj));
            acc += ee * xv;
            den += ee;
        }
        gv = acc / den + gbs[j];
        g[(size_t)d * HC + j] = gv;
    }
    float s = gv, ss = gv * gv;
    for (int m = 32; m >= 1; m >>= 1) { s += __shfl_xor(s, m); ss += __shfl_xor(ss, m); }
    __shared__ float sr[4], ssr[4];
    const int w = t >> 6;
    if ((t & 63) == 0) { sr[w] = s; ssr[w] = ss; }
    __syncthreads();
    if (t == 0) part[blockIdx.x] = make_float2(sr[0] + sr[1] + sr[2] + sr[3],
                                               ssr[0] + ssr[1] + ssr[2] + ssr[3]);
}

// ---- reduce block partials -> stats[0..1] ------------------------------------
__global__ __launch_bounds__(256) void k_red(
    const float2* __restrict__ part, int n, double* __restrict__ out)
{
    const int t = threadIdx.x;
    double s = 0.0, ss = 0.0;
    for (int i = t; i < n; i += 256) {
        float2 p = part[i];
        s += (double)p.x; ss += (double)p.y;
    }
    for (int m = 32; m >= 1; m >>= 1) { s += __shfl_xor(s, m); ss += __shfl_xor(ss, m); }
    __shared__ double sr[4], ssr[4];
    const int w = t >> 6;
    if ((t & 63) == 0) { sr[w] = s; ssr[w] = ss; }
    __syncthreads();
    if (t == 0) {
        out[0] = sr[0] + sr[1] + sr[2] + sr[3];
        out[1] = ssr[0] + ssr[1] + ssr[2] + ssr[3];
    }
}

// ---- apply LN1 + relu + linear(32->16) + partial stats for LN2 ---------------
__global__ __launch_bounds__(256) void k_mid(
    const float* __restrict__ g,
    const float* __restrict__ n1w, const float* __restrict__ n1b,
    const float* __restrict__ linW, const float* __restrict__ linb,
    const double* __restrict__ stats1, float* __restrict__ g2,
    float2* __restrict__ part)
{
    __shared__ float Ws[HC * NC];
    __shared__ float rs[16][HC + 1];
    const int t = threadIdx.x;
    for (int i = t; i < HC * NC; i += 256) Ws[i] = linW[i];
    const double cnt = (double)N_NODES * HC;
    const double mud = stats1[0] / cnt;
    const float mu  = (float)mud;
    const float var = (float)(stats1[1] / cnt - mud * mud);
    const float inv = rsqrtf(var + EPS);
    const int n0 = blockIdx.x * 16;
    for (int i = t; i < 16 * HC; i += 256) {
        int r = i >> 5, j = i & 31;
        int n = n0 + r;
        float v = (n < N_NODES) ? g[(size_t)n * HC + j] : mu;
        v = (v - mu) * inv * n1w[j] + n1b[j];
        rs[r][j] = fmaxf(v, 0.f);
    }
    __syncthreads();
    const int r = t >> 4, c = t & 15;
    const int n = n0 + r;
    float acc = linb[c];
#pragma unroll
    for (int j = 0; j < HC; ++j) acc += rs[r][j] * Ws[j * NC + c];
    float val = (n < N_NODES) ? acc : 0.f;
    if (n < N_NODES) g2[(size_t)n * NC + c] = acc;
    float s = val, ss = val * val;
    for (int m = 32; m >= 1; m >>= 1) { s += __shfl_xor(s, m); ss += __shfl_xor(ss, m); }
    __shared__ float sr[4], ssr[4];
    const int w = t >> 6;
    if ((t & 63) == 0) { sr[w] = s; ssr[w] = ss; }
    __syncthreads();
    if (t == 0) part[blockIdx.x] = make_float2(sr[0] + sr[1] + sr[2] + sr[3],
                                               ssr[0] + ssr[1] + ssr[2] + ssr[3]);
}

// ---- fused: apply LN2 + residual + relu + jk-max, then next-layer transforms -
__global__ __launch_bounds__(256) void k_ftrans(
    const float* __restrict__ g2, const float* __restrict__ n2w,
    const float* __restrict__ n2b, const double* __restrict__ stats2,
    float* __restrict__ h, float* __restrict__ jk,
    const float* __restrict__ Wl, const float* __restrict__ bl,
    const float* __restrict__ Wr, const float* __restrict__ br,
    unsigned short* __restrict__ xl, unsigned short* __restrict__ xr)
{
    __shared__ float Wls[NC * HC], Wrs[NC * HC];
    __shared__ float hs[8][NC + 1];
    const int t = threadIdx.x;
    for (int i = t; i < NC * HC; i += 256) { Wls[i] = Wl[i]; Wrs[i] = Wr[i]; }
    const double cnt = (double)N_NODES * NC;
    const double mud = stats2[0] / cnt;
    const float mu  = (float)mud;
    const float var = (float)(stats2[1] / cnt - mud * mud);
    const float inv = rsqrtf(var + EPS);
    const int n0 = blockIdx.x * 8;
    if (t < 8 * NC) {
        int r = t >> 4, c = t & 15;
        int n = n0 + r;
        if (n < N_NODES) {
            size_t idx = (size_t)n * NC + c;
            float v = (g2[idx] - mu) * inv * n2w[c] + n2b[c];
            float hn = fmaxf(v + h[idx], 0.f);
            h[idx] = hn;
            jk[idx] = fmaxf(jk[idx], hn);
            hs[r][c] = hn;
        } else hs[r][c] = 0.f;
    }
    __syncthreads();
    const int r = t >> 5;
    const int j = t & 31;
    const int n = n0 + r;
    float al = bl[j], ar = br[j];
#pragma unroll
    for (int c = 0; c < NC; ++c) {
        float hv = hs[r][c];
        al += hv * Wls[c * HC + j];
        ar += hv * Wrs[c * HC + j];
    }
    if (n < N_NODES) {
        xl[(size_t)n * HC + j] = f2bf(al);
        xr[(size_t)n * HC + j] = f2bf(ar);
    }
}

// ---- last layer: apply LN2, residual + relu, update h and jk-max -------------
__global__ __launch_bounds__(256) void k_final(
    const float* __restrict__ g2, const float* __restrict__ n2w,
    const float* __restrict__ n2b, const double* __restrict__ stats2,
    float* __restrict__ h, float* __restrict__ jk)
{
    const int i = blockIdx.x * 256 + threadIdx.x;
    if (i >= N_NODES * NC) return;
    const double cnt = (double)N_NODES * NC;
    const double mud = stats2[0] / cnt;
    const float mu  = (float)mud;
    const float var = (float)(stats2[1] / cnt - mud * mud);
    const float inv = rsqrtf(var + EPS);
    const int c = i & (NC - 1);
    float v = (g2[i] - mu) * inv * n2w[c] + n2b[c];
    float hn = fmaxf(v + h[i], 0.f);
    h[i] = hn;
    jk[i] = fmaxf(jk[i], hn);
}

extern "C" void kernel_launch(void* const* d_in, const int* in_sizes, int n_in,
                              void* d_out, int out_size, void* d_ws, size_t ws_size,
                              hipStream_t stream)
{
    const float* x     = (const float*)d_in[0];
    const int*   eidx  = (const int*)d_in[1];
    const float* eattr = (const float*)d_in[2];
    const float* embW  = (const float*)d_in[3];
    const float* embB  = (const float*)d_in[4];
    const float* ln0w  = (const float*)d_in[5];
    const float* ln0b  = (const float*)d_in[6];
    const float* Wl    = (const float*)d_in[7];
    const float* bl    = (const float*)d_in[8];
    const float* Wr    = (const float*)d_in[9];
    const float* br    = (const float*)d_in[10];
    const float* We    = (const float*)d_in[11];
    const float* att   = (const float*)d_in[12];
    const float* gatb  = (const float*)d_in[13];
    const float* n1w   = (const float*)d_in[14];
    const float* n1b   = (const float*)d_in[15];
    const float* linW  = (const float*)d_in[16];
    const float* linb  = (const float*)d_in[17];
    const float* n2w   = (const float*)d_in[18];
    const float* n2b   = (const float*)d_in[19];
    float* out = (float*)d_out;

    // ---- workspace layout (R8-proven structure; tmp_rec takes tmp_ea's union) -
    char* ws = (char*)d_ws;
    double* stats = (double*)ws;                 // [0..1]=LN1, [2..3]=LN2
    char* p = ws + 1024;
    int* bcnt = (int*)p; p += 1024;              // 256 ints (zeroed)
    int* bbase = (int*)p; p += 4096;             // 257 ints
    int* bcur  = (int*)p; p += 1024;             // 256 ints
    int* offsets = (int*)p; p += (size_t)(N_NODES + 64) * 4;
    float* g = (float*)p; p += (size_t)N_NODES * HC * 4;
    int4* csr = (int4*)p; p += (size_t)N_EDGES * 16;
    // union: tmp_rec (CSR build only) <-> h/xl/xr/g2 (layers) — both 25.6 MB
    int4* tmp_rec = (int4*)p;
    char* q = p;
    p += (size_t)N_EDGES * 16;
    float* hq = (float*)q; q += (size_t)N_NODES * NC * 4;
    unsigned short* xlq = (unsigned short*)q; q += (size_t)N_NODES * HC * 2;
    unsigned short* xrq = (unsigned short*)q; q += (size_t)N_NODES * HC * 2;
    float* g2q = (float*)q;
    float2* part1 = (float2*)p; p += (size_t)AGG_BLKS * 8;
    float2* part2 = (float2*)p; p += (size_t)MID_BLKS * 8;

    const int* srcp = eidx;
    const int* dstp = eidx + N_EDGES;

    // CSR build: bucket sort (LDS-staged, bf16 eattr packed into 16B records)
    hipMemsetAsync(bcnt, 0, 1024, stream);
    k_bhist<<<P1_BLKS, 256, 0, stream>>>(dstp, bcnt);
    k_bscan<<<1, 256, 0, stream>>>(bcnt, bbase, bcur);
    k_pass1<<<P1_BLKS, 256, 0, stream>>>(srcp, dstp, (const float4*)eattr,
                                         bcur, tmp_rec);
    k_pass2<<<NBUCK, 256, 0, stream>>>(bbase, tmp_rec, offsets, csr);

    k_embed<<<(N_NODES + 15) / 16, 256, 0, stream>>>(x, embW, embB, ln0w, ln0b, hq, out);

    // layer 0
    k_trans<<<(N_NODES + 7) / 8, 256, 0, stream>>>(hq, Wl, bl, Wr, br, xlq, xrq);
    k_agg<<<AGG_BLKS, 256, 0, stream>>>(
        offsets, csr, We, att, gatb, xlq, xrq, g, part1);
    k_red<<<1, 256, 0, stream>>>(part1, AGG_BLKS, stats);
    k_mid<<<MID_BLKS, 256, 0, stream>>>(
        g, n1w, n1b, linW, linb, stats, g2q, part2);
    k_red<<<1, 256, 0, stream>>>(part2, MID_BLKS, stats + 2);
    k_ftrans<<<(N_NODES + 7) / 8, 256, 0, stream>>>(
        g2q, n2w, n2b, stats + 2, hq, out,
        Wl + NC * HC, bl + HC, Wr + NC * HC, br + HC, xlq, xrq);
    // layer 1
    k_agg<<<AGG_BLKS, 256, 0, stream>>>(
        offsets, csr, We + NED * HC, att + HC, gatb + HC, xlq, xrq, g, part1);
    k_red<<<1, 256, 0, stream>>>(part1, AGG_BLKS, stats);
    k_mid<<<MID_BLKS, 256, 0, stream>>>(
        g, n1w + HC, n1b + HC, linW + HC * NC, linb + NC, stats, g2q, part2);
    k_red<<<1, 256, 0, stream>>>(part2, MID_BLKS, stats + 2);
    k_final<<<(N_NODES * NC + 255) / 256, 256, 0, stream>>>(
        g2q, n2w + NC, n2b + NC, stats + 2, hq, out);
}

// Round 11
// 478.429 us; speedup vs baseline: 3.0620x; 1.0320x over previous
//
#include <hip/hip_runtime.h>

#define N_NODES 100000
#define N_EDGES 1600000
#define NF 128
#define NC 16
#define NH 2
#define HC 32   // NH*NC
#define NL 2
#define NED 4
#define EPS 1e-5f
#define NEG 0.2f
#define NBUCK 196                    // ceil(N_NODES / 512)
#define P1_CHUNK 4096
#define P1_BLKS ((N_EDGES + P1_CHUNK - 1) / P1_CHUNK)   // 391
#define AGG_BLKS ((N_NODES + 7) / 8)               // 12500
#define MID_BLKS ((N_NODES + 15) / 16)             // 6250

// ---- bf16 helpers (manual, RTN-even) -----------------------------------------
__device__ __forceinline__ unsigned short f2bf(float f) {
    unsigned int u = __float_as_uint(f);
    u += 0x7fffu + ((u >> 16) & 1u);
    return (unsigned short)(u >> 16);
}
__device__ __forceinline__ float bf2f(unsigned short u) {
    return __uint_as_float(((unsigned int)u) << 16);
}
__device__ __forceinline__ unsigned int pack_bf2(float a, float b) {
    return (unsigned int)f2bf(a) | ((unsigned int)f2bf(b) << 16);
}
__device__ __forceinline__ float bflo(int u) {
    return __uint_as_float(((unsigned int)u) << 16);
}
__device__ __forceinline__ float bfhi(int u) {
    return __uint_as_float(((unsigned int)u) & 0xffff0000u);
}
// 32-bit byte-offset gather from uniform base (emits saddr+voffset form)
__device__ __forceinline__ float bf_gather(const unsigned short* base, unsigned boff) {
    return bf2f(*(const unsigned short*)((const char*)base + boff));
}

// ---------------- embed: h = relu(node_LN(x @ W + b)) ; jk = h ----------------
// W transposed in LDS so the GEMM reads both operands as float4 (ds_read_b128)
__global__ __launch_bounds__(256) void k_embed(
    const float* __restrict__ x, const float* __restrict__ W,
    const float* __restrict__ b, const float* __restrict__ lnw,
    const float* __restrict__ lnb, float* __restrict__ h, float* __restrict__ jk)
{
    __shared__ __align__(16) float WsT[NC][NF + 4];   // [c][f]
    __shared__ __align__(16) float xs[16][NF + 4];
    const int t = threadIdx.x;
    for (int i = t; i < NF * NC; i += 256) {
        int f = i >> 4, c = i & 15;
        WsT[c][f] = W[i];
    }
    const int n0 = blockIdx.x * 16;
    const float4* x4 = (const float4*)x;
    for (int i = t; i < 16 * (NF / 4); i += 256) {    // 512 float4
        int r = i >> 5, f4 = i & 31;
        int n = n0 + r;
        float4 v = (n < N_NODES) ? x4[(size_t)n * (NF / 4) + f4]
                                 : make_float4(0.f, 0.f, 0.f, 0.f);
        *(float4*)&xs[r][f4 * 4] = v;
    }
    __syncthreads();
    const int r = t >> 4;
    const int c = t & 15;
    const int n = n0 + r;
    float acc = b[c];
#pragma unroll
    for (int f4 = 0; f4 < NF / 4; ++f4) {
        float4 xv = *(const float4*)&xs[r][f4 * 4];
        float4 wv = *(const float4*)&WsT[c][f4 * 4];
        acc += xv.x * wv.x + xv.y * wv.y + xv.z * wv.z + xv.w * wv.w;
    }
    float s = acc;
    for (int m = 8; m >= 1; m >>= 1) s += __shfl_xor(s, m, 16);
    float mu = s * (1.f / 16.f);
    float d = acc - mu;
    float v = d * d;
    for (int m = 8; m >= 1; m >>= 1) v += __shfl_xor(v, m, 16);
    float inv = rsqrtf(v * (1.f / 16.f) + EPS);
    float out = fmaxf(d * inv * lnw[c] + lnb[c], 0.f);
    if (n < N_NODES) {
        h[(size_t)n * NC + c]  = out;
        jk[(size_t)n * NC + c] = out;
    }
}

// ---- bucket histogram (bucket = dst >> 9), LDS-staged ------------------------
__global__ __launch_bounds__(256) void k_bhist(
    const int* __restrict__ dst, int* __restrict__ bcnt)
{
    __shared__ int hist[256];
    const int t = threadIdx.x;
    hist[t] = 0;
    __syncthreads();
    const int e0 = blockIdx.x * P1_CHUNK;
    const int cnt = min(P1_CHUNK, N_EDGES - e0);
    for (int i = t; i < cnt; i += 256)
        atomicAdd(&hist[dst[e0 + i] >> 9], 1);
    __syncthreads();
    if (hist[t] > 0) atomicAdd(&bcnt[t], hist[t]);
}

// ---- scan 196 bucket counts -> bases + working cursors -----------------------
__global__ __launch_bounds__(256) void k_bscan(
    const int* __restrict__ bcnt, int* __restrict__ bbase, int* __restrict__ bcur)
{
    __shared__ int tmp[256];
    const int t = threadIdx.x;
    int v0 = bcnt[t];
    tmp[t] = v0;
    __syncthreads();
    for (int off = 1; off < 256; off <<= 1) {
        int v = (t >= off) ? tmp[t - off] : 0;
        __syncthreads();
        tmp[t] += v;
        __syncthreads();
    }
    int excl = tmp[t] - v0;
    bbase[t] = excl;
    bcur[t]  = excl;
    if (t == 255) bbase[256] = tmp[t];   // == N_EDGES
}

// ---- pass1: LDS-staged bucket scatter; packs {src, dl, bf16(ea)x4} -----------
// staged payload: {src, (e<<9)|dst_local}; e < 2^21, dst_local < 512
__global__ __launch_bounds__(256) void k_pass1(
    const int* __restrict__ src, const int* __restrict__ dst,
    const float4* __restrict__ ea4, int* __restrict__ bcur,
    int4* __restrict__ tmp_rec)
{
    __shared__ int2 stage[P1_CHUNK];                 // 32 KB
    __shared__ unsigned char bstage[P1_CHUNK];       // 4 KB
    __shared__ int hist[256];
    __shared__ int exc[256];
    __shared__ int gbase[256];
    __shared__ int scanbuf[256];
    const int t = threadIdx.x;
    const int e0 = blockIdx.x * P1_CHUNK;
    const int cnt = min(P1_CHUNK, N_EDGES - e0);
    hist[t] = 0;
    __syncthreads();
    int mys[16], myb[16], myp[16];
    int nv = 0;
#pragma unroll
    for (int k = 0; k < 16; ++k) {
        int i = k * 256 + t;
        if (i < cnt) {
            int e = e0 + i;
            int d = dst[e];
            mys[nv] = src[e];
            myb[nv] = d >> 9;
            myp[nv] = (e << 9) | (d & 511);
            atomicAdd(&hist[d >> 9], 1);
            ++nv;
        }
    }
    __syncthreads();
    int hv = hist[t];
    scanbuf[t] = hv;
    __syncthreads();
    for (int off = 1; off < 256; off <<= 1) {
        int v = (t >= off) ? scanbuf[t - off] : 0;
        __syncthreads();
        scanbuf[t] += v;
        __syncthreads();
    }
    int ex = scanbuf[t] - hv;
    hist[t] = ex;            // becomes local cursor
    exc[t]  = ex;
    __syncthreads();
    for (int k = 0; k < nv; ++k) {
        int pos = atomicAdd(&hist[myb[k]], 1);
        stage[pos]  = make_int2(mys[k], myp[k]);
        bstage[pos] = (unsigned char)myb[k];
    }
    __syncthreads();
    {
        int c = hist[t] - exc[t];
        gbase[t] = (c > 0) ? atomicAdd(&bcur[t], c) : 0;
    }
    __syncthreads();
    // flush: bucket runs -> contiguous slots; ea gather stays in chunk window
    for (int i = t; i < cnt; i += 256) {
        int b = bstage[i];
        int2 se = stage[i];
        int e  = (int)(((unsigned int)se.y) >> 9);
        int dl = se.y & 511;
        float4 ea = ea4[e];
        int gpos = gbase[b] + (i - exc[b]);
        tmp_rec[gpos] = make_int4(se.x, dl,
                                  (int)pack_bf2(ea.x, ea.y),
                                  (int)pack_bf2(ea.z, ea.w));
    }
}

// ---- pass2: one block per bucket; per-dst LDS hist+scan -> offsets + CSR -----
__global__ __launch_bounds__(256) void k_pass2(
    const int* __restrict__ bbase, const int4* __restrict__ tmp_rec,
    int* __restrict__ offsets, int4* __restrict__ csr)
{
    __shared__ int hist[512];
    __shared__ int cur[512];
    __shared__ int scanbuf[256];
    const int b = blockIdx.x, t = threadIdx.x;
    const int ebeg = bbase[b], eend = bbase[b + 1];
    hist[t] = 0; hist[t + 256] = 0;
    __syncthreads();
    for (int i = ebeg + t; i < eend; i += 256)
        atomicAdd(&hist[tmp_rec[i].y], 1);
    __syncthreads();
    int a0 = hist[2 * t], a1 = hist[2 * t + 1];
    int pair = a0 + a1;
    scanbuf[t] = pair;
    __syncthreads();
    for (int off = 1; off < 256; off <<= 1) {
        int v = (t >= off) ? scanbuf[t - off] : 0;
        __syncthreads();
        scanbuf[t] += v;
        __syncthreads();
    }
    int ex2 = scanbuf[t] - pair;
    cur[2 * t]     = ex2;
    cur[2 * t + 1] = ex2 + a0;
    __syncthreads();
    const int n0 = b * 512;
#pragma unroll
    for (int k = 0; k < 2; ++k) {
        int i = t + k * 256;
        int n = n0 + i;
        if (n < N_NODES) offsets[n] = ebeg + cur[i];
    }
    if (b == NBUCK - 1 && t == 0) offsets[N_NODES] = N_EDGES;
    __syncthreads();
    // permute (writes stay inside this bucket's L2-resident window)
    for (int i = ebeg + t; i < eend; i += 256) {
        int4 rec = tmp_rec[i];
        int pos = ebeg + atomicAdd(&cur[rec.y], 1);
        csr[pos] = rec;   // {src, dl(unused later), eab01, eab23}
    }
}

// ---- per-layer: xl/xr transforms (bf16 out) ----------------------------------
__global__ __launch_bounds__(256) void k_trans(
    const float* __restrict__ h, const float* __restrict__ Wl, const float* __restrict__ bl,
    const float* __restrict__ Wr, const float* __restrict__ br,
    unsigned short* __restrict__ xl, unsigned short* __restrict__ xr)
{
    __shared__ float Wls[NC * HC], Wrs[NC * HC];
    __shared__ float hs[8][NC + 1];
    const int t = threadIdx.x;
    for (int i = t; i < NC * HC; i += 256) { Wls[i] = Wl[i]; Wrs[i] = Wr[i]; }
    const int n0 = blockIdx.x * 8;
    for (int i = t; i < 8 * NC; i += 256) {
        int r = i >> 4, c = i & 15;
        int n = n0 + r;
        hs[r][c] = (n < N_NODES) ? h[(size_t)n * NC + c] : 0.f;
    }
    __syncthreads();
    const int r = t >> 5;
    const int j = t & 31;
    const int n = n0 + r;
    float al = bl[j], ar = br[j];
#pragma unroll
    for (int c = 0; c < NC; ++c) {
        float hv = hs[r][c];
        al += hv * Wls[c * HC + j];
        ar += hv * Wrs[c * HC + j];
    }
    if (n < N_NODES) {
        xl[(size_t)n * HC + j] = f2bf(al);
        xr[(size_t)n * HC + j] = f2bf(ar);
    }
}

__device__ __forceinline__ float head_sum(float p) {
    p += __shfl_xor(p, 1, 16);
    p += __shfl_xor(p, 2, 16);
    p += __shfl_xor(p, 4, 16);
    p += __shfl_xor(p, 8, 16);
    return p;
}

// ---- aggregation: single 16B record/edge, unroll-4; partial stats ------------
__global__ __launch_bounds__(256) void k_agg(
    const int* __restrict__ offsets, const int4* __restrict__ csr,
    const float* __restrict__ We, const float* __restrict__ att,
    const float* __restrict__ gat_b,
    const unsigned short* __restrict__ xl, const unsigned short* __restrict__ xr,
    float* __restrict__ g, float2* __restrict__ part)
{
    __shared__ float Wes[NED * HC];
    __shared__ float atts[HC], gbs[HC];
    const int t = threadIdx.x;
    if (t < NED * HC) Wes[t] = We[t];
    if (t < HC) { atts[t] = att[t]; gbs[t] = gat_b[t]; }
    __syncthreads();
    const int grp = t >> 5;
    const int j   = t & 31;
    const int d = blockIdx.x * 8 + grp;
    float gv = 0.f;
    if (d < N_NODES) {
        const float aj = atts[j];
        const float w0 = Wes[j], w1 = Wes[HC + j], w2 = Wes[2 * HC + j], w3 = Wes[3 * HC + j];
        const unsigned jb = (unsigned)(j << 1);     // channel byte offset
        const float xld = bf_gather(xl, ((unsigned)d << 6) + jb);
        const float xrd = bf_gather(xr, ((unsigned)d << 6) + jb);
        // self-loop (ew = 0); logits tiny: exp without segment-max is exact enough
        float m = xld + xrd;
        m = fmaxf(m, NEG * m);
        float eh = __expf(head_sum(m * aj));
        float acc = eh * xld;
        float den = eh;
        const int base = offsets[d];
        const int deg  = offsets[d + 1] - base;
        int k = 0;
        for (; k + 4 <= deg; k += 4) {
            const int b0 = base + k;
            const int4 r0 = csr[b0],     r1 = csr[b0 + 1];
            const int4 r2 = csr[b0 + 2], r3 = csr[b0 + 3];
            const float x0 = bf_gather(xl, ((unsigned)r0.x << 6) + jb);
            const float x1 = bf_gather(xl, ((unsigned)r1.x << 6) + jb);
            const float x2 = bf_gather(xl, ((unsigned)r2.x << 6) + jb);
            const float x3 = bf_gather(xl, ((unsigned)r3.x << 6) + jb);
            float m0 = x0 + xrd + bflo(r0.z) * w0 + bfhi(r0.z) * w1 + bflo(r0.w) * w2 + bfhi(r0.w) * w3;
            float m1 = x1 + xrd + bflo(r1.z) * w0 + bfhi(r1.z) * w1 + bflo(r1.w) * w2 + bfhi(r1.w) * w3;
            float m2 = x2 + xrd + bflo(r2.z) * w0 + bfhi(r2.z) * w1 + bflo(r2.w) * w2 + bfhi(r2.w) * w3;
            float m3 = x3 + xrd + bflo(r3.z) * w0 + bfhi(r3.z) * w1 + bflo(r3.w) * w2 + bfhi(r3.w) * w3;
            m0 = fmaxf(m0, NEG * m0);
            m1 = fmaxf(m1, NEG * m1);
            m2 = fmaxf(m2, NEG * m2);
            m3 = fmaxf(m3, NEG * m3);
            float p0 = m0 * aj, p1 = m1 * aj, p2 = m2 * aj, p3 = m3 * aj;
            p0 += __shfl_xor(p0, 1, 16); p1 += __shfl_xor(p1, 1, 16);
            p2 += __shfl_xor(p2, 1, 16); p3 += __shfl_xor(p3, 1, 16);
            p0 += __shfl_xor(p0, 2, 16); p1 += __shfl_xor(p1, 2, 16);
            p2 += __shfl_xor(p2, 2, 16); p3 += __shfl_xor(p3, 2, 16);
            p0 += __shfl_xor(p0, 4, 16); p1 += __shfl_xor(p1, 4, 16);
            p2 += __shfl_xor(p2, 4, 16); p3 += __shfl_xor(p3, 4, 16);
            p0 += __shfl_xor(p0, 8, 16); p1 += __shfl_xor(p1, 8, 16);
            p2 += __shfl_xor(p2, 8, 16); p3 += __shfl_xor(p3, 8, 16);
            const float ee0 = __expf(p0), ee1 = __expf(p1);
            const float ee2 = __expf(p2), ee3 = __expf(p3);
            acc += ee0 * x0 + ee1 * x1 + ee2 * x2 + ee3 * x3;
            den += ee0 + ee1 + ee2 + ee3;
        }
        for (; k < deg; ++k) {
            const int4 r = csr[base + k];
            const float xv = bf_gather(xl, ((unsigned)r.x << 6) + jb);
            float mm = xv + xrd + bflo(r.z) * w0 + bfhi(r.z) * w1 + bflo(r.w) * w2 + bfhi(r.w) * w3;
            mm = fmaxf(mm, NEG * mm);
            const float ee = __expf(head_sum(mm * aj));
            acc += ee * xv;
            den += ee;
        }
        gv = acc / den + gbs[j];
        g[(size_t)d * HC + j] = gv;
    }
    float s = gv, ss = gv * gv;
    for (int m = 32; m >= 1; m >>= 1) { s += __shfl_xor(s, m); ss += __shfl_xor(ss, m); }
    __shared__ float sr[4], ssr[4];
    const int w = t >> 6;
    if ((t & 63) == 0) { sr[w] = s; ssr[w] = ss; }
    __syncthreads();
    if (t == 0) part[blockIdx.x] = make_float2(sr[0] + sr[1] + sr[2] + sr[3],
                                               ssr[0] + ssr[1] + ssr[2] + ssr[3]);
}

// ---- reduce block partials -> stats[0..1] ------------------------------------
__global__ __launch_bounds__(256) void k_red(
    const float2* __restrict__ part, int n, double* __restrict__ out)
{
    const int t = threadIdx.x;
    double s = 0.0, ss = 0.0;
    for (int i = t; i < n; i += 256) {
        float2 p = part[i];
        s += (double)p.x; ss += (double)p.y;
    }
    for (int m = 32; m >= 1; m >>= 1) { s += __shfl_xor(s, m); ss += __shfl_xor(ss, m); }
    __shared__ double sr[4], ssr[4];
    const int w = t >> 6;
    if ((t & 63) == 0) { sr[w] = s; ssr[w] = ss; }
    __syncthreads();
    if (t == 0) {
        out[0] = sr[0] + sr[1] + sr[2] + sr[3];
        out[1] = ssr[0] + ssr[1] + ssr[2] + ssr[3];
    }
}

// ---- apply LN1 + relu + linear(32->16) + partial stats for LN2 ---------------
__global__ __launch_bounds__(256) void k_mid(
    const float* __restrict__ g,
    const float* __restrict__ n1w, const float* __restrict__ n1b,
    const float* __restrict__ linW, const float* __restrict__ linb,
    const double* __restrict__ stats1, float* __restrict__ g2,
    float2* __restrict__ part)
{
    __shared__ float Ws[HC * NC];
    __shared__ float rs[16][HC + 1];
    const int t = threadIdx.x;
    for (int i = t; i < HC * NC; i += 256) Ws[i] = linW[i];
    const double cnt = (double)N_NODES * HC;
    const double mud = stats1[0] / cnt;
    const float mu  = (float)mud;
    const float var = (float)(stats1[1] / cnt - mud * mud);
    const float inv = rsqrtf(var + EPS);
    const int n0 = blockIdx.x * 16;
    for (int i = t; i < 16 * HC; i += 256) {
        int r = i >> 5, j = i & 31;
        int n = n0 + r;
        float v = (n < N_NODES) ? g[(size_t)n * HC + j] : mu;
        v = (v - mu) * inv * n1w[j] + n1b[j];
        rs[r][j] = fmaxf(v, 0.f);
    }
    __syncthreads();
    const int r = t >> 4, c = t & 15;
    const int n = n0 + r;
    float acc = linb[c];
#pragma unroll
    for (int j = 0; j < HC; ++j) acc += rs[r][j] * Ws[j * NC + c];
    float val = (n < N_NODES) ? acc : 0.f;
    if (n < N_NODES) g2[(size_t)n * NC + c] = acc;
    float s = val, ss = val * val;
    for (int m = 32; m >= 1; m >>= 1) { s += __shfl_xor(s, m); ss += __shfl_xor(ss, m); }
    __shared__ float sr[4], ssr[4];
    const int w = t >> 6;
    if ((t & 63) == 0) { sr[w] = s; ssr[w] = ss; }
    __syncthreads();
    if (t == 0) part[blockIdx.x] = make_float2(sr[0] + sr[1] + sr[2] + sr[3],
                                               ssr[0] + ssr[1] + ssr[2] + ssr[3]);
}

// ---- fused: apply LN2 + residual + relu + jk-max, then next-layer transforms -
__global__ __launch_bounds__(256) void k_ftrans(
    const float* __restrict__ g2, const float* __restrict__ n2w,
    const float* __restrict__ n2b, const double* __restrict__ stats2,
    float* __restrict__ h, float* __restrict__ jk,
    const float* __restrict__ Wl, const float* __restrict__ bl,
    const float* __restrict__ Wr, const float* __restrict__ br,
    unsigned short* __restrict__ xl, unsigned short* __restrict__ xr)
{
    __shared__ float Wls[NC * HC], Wrs[NC * HC];
    __shared__ float hs[8][NC + 1];
    const int t = threadIdx.x;
    for (int i = t; i < NC * HC; i += 256) { Wls[i] = Wl[i]; Wrs[i] = Wr[i]; }
    const double cnt = (double)N_NODES * NC;
    const double mud = stats2[0] / cnt;
    const float mu  = (float)mud;
    const float var = (float)(stats2[1] / cnt - mud * mud);
    const float inv = rsqrtf(var + EPS);
    const int n0 = blockIdx.x * 8;
    if (t < 8 * NC) {
        int r = t >> 4, c = t & 15;
        int n = n0 + r;
        if (n < N_NODES) {
            size_t idx = (size_t)n * NC + c;
            float v = (g2[idx] - mu) * inv * n2w[c] + n2b[c];
            float hn = fmaxf(v + h[idx], 0.f);
            h[idx] = hn;
            jk[idx] = fmaxf(jk[idx], hn);
            hs[r][c] = hn;
        } else hs[r][c] = 0.f;
    }
    __syncthreads();
    const int r = t >> 5;
    const int j = t & 31;
    const int n = n0 + r;
    float al = bl[j], ar = br[j];
#pragma unroll
    for (int c = 0; c < NC; ++c) {
        float hv = hs[r][c];
        al += hv * Wls[c * HC + j];
        ar += hv * Wrs[c * HC + j];
    }
    if (n < N_NODES) {
        xl[(size_t)n * HC + j] = f2bf(al);
        xr[(size_t)n * HC + j] = f2bf(ar);
    }
}

// ---- last layer: apply LN2, residual + relu, update h and jk-max -------------
__global__ __launch_bounds__(256) void k_final(
    const float* __restrict__ g2, const float* __restrict__ n2w,
    const float* __restrict__ n2b, const double* __restrict__ stats2,
    float* __restrict__ h, float* __restrict__ jk)
{
    const int i = blockIdx.x * 256 + threadIdx.x;
    if (i >= N_NODES * NC) return;
    const double cnt = (double)N_NODES * NC;
    const double mud = stats2[0] / cnt;
    const float mu  = (float)mud;
    const float var = (float)(stats2[1] / cnt - mud * mud);
    const float inv = rsqrtf(var + EPS);
    const int c = i & (NC - 1);
    float v = (g2[i] - mu) * inv * n2w[c] + n2b[c];
    float hn = fmaxf(v + h[i], 0.f);
    h[i] = hn;
    jk[i] = fmaxf(jk[i], hn);
}

extern "C" void kernel_launch(void* const* d_in, const int* in_sizes, int n_in,
                              void* d_out, int out_size, void* d_ws, size_t ws_size,
                              hipStream_t stream)
{
    const float* x     = (const float*)d_in[0];
    const int*   eidx  = (const int*)d_in[1];
    const float* eattr = (const float*)d_in[2];
    const float* embW  = (const float*)d_in[3];
    const float* embB  = (const float*)d_in[4];
    const float* ln0w  = (const float*)d_in[5];
    const float* ln0b  = (const float*)d_in[6];
    const float* Wl    = (const float*)d_in[7];
    const float* bl    = (const float*)d_in[8];
    const float* Wr    = (const float*)d_in[9];
    const float* br    = (const float*)d_in[10];
    const float* We    = (const float*)d_in[11];
    const float* att   = (const float*)d_in[12];
    const float* gatb  = (const float*)d_in[13];
    const float* n1w   = (const float*)d_in[14];
    const float* n1b   = (const float*)d_in[15];
    const float* linW  = (const float*)d_in[16];
    const float* linb  = (const float*)d_in[17];
    const float* n2w   = (const float*)d_in[18];
    const float* n2b   = (const float*)d_in[19];
    float* out = (float*)d_out;

    // ---- workspace layout (R10-proven structure) ----
    char* ws = (char*)d_ws;
    double* stats = (double*)ws;                 // [0..1]=LN1, [2..3]=LN2
    char* p = ws + 1024;
    int* bcnt = (int*)p; p += 1024;              // 256 ints (zeroed)
    int* bbase = (int*)p; p += 4096;             // 257 ints
    int* bcur  = (int*)p; p += 1024;             // 256 ints
    int* offsets = (int*)p; p += (size_t)(N_NODES + 64) * 4;
    float* g = (float*)p; p += (size_t)N_NODES * HC * 4;
    int4* csr = (int4*)p; p += (size_t)N_EDGES * 16;
    // union: tmp_rec (CSR build only) <-> h/xl/xr/g2 (layers) — both 25.6 MB
    int4* tmp_rec = (int4*)p;
    char* q = p;
    p += (size_t)N_EDGES * 16;
    float* hq = (float*)q; q += (size_t)N_NODES * NC * 4;
    unsigned short* xlq = (unsigned short*)q; q += (size_t)N_NODES * HC * 2;
    unsigned short* xrq = (unsigned short*)q; q += (size_t)N_NODES * HC * 2;
    float* g2q = (float*)q;
    float2* part1 = (float2*)p; p += (size_t)AGG_BLKS * 8;
    float2* part2 = (float2*)p; p += (size_t)MID_BLKS * 8;

    const int* srcp = eidx;
    const int* dstp = eidx + N_EDGES;

    // CSR build: bucket sort (LDS-staged, bf16 eattr packed into 16B records)
    hipMemsetAsync(bcnt, 0, 1024, stream);
    k_bhist<<<P1_BLKS, 256, 0, stream>>>(dstp, bcnt);
    k_bscan<<<1, 256, 0, stream>>>(bcnt, bbase, bcur);
    k_pass1<<<P1_BLKS, 256, 0, stream>>>(srcp, dstp, (const float4*)eattr,
                                         bcur, tmp_rec);
    k_pass2<<<NBUCK, 256, 0, stream>>>(bbase, tmp_rec, offsets, csr);

    k_embed<<<(N_NODES + 15) / 16, 256, 0, stream>>>(x, embW, embB, ln0w, ln0b, hq, out);

    // layer 0
    k_trans<<<(N_NODES + 7) / 8, 256, 0, stream>>>(hq, Wl, bl, Wr, br, xlq, xrq);
    k_agg<<<AGG_BLKS, 256, 0, stream>>>(
        offsets, csr, We, att, gatb, xlq, xrq, g, part1);
    k_red<<<1, 256, 0, stream>>>(part1, AGG_BLKS, stats);
    k_mid<<<MID_BLKS, 256, 0, stream>>>(
        g, n1w, n1b, linW, linb, stats, g2q, part2);
    k_red<<<1, 256, 0, stream>>>(part2, MID_BLKS, stats + 2);
    k_ftrans<<<(N_NODES + 7) / 8, 256, 0, stream>>>(
        g2q, n2w, n2b, stats + 2, hq, out,
        Wl + NC * HC, bl + HC, Wr + NC * HC, br + HC, xlq, xrq);
    // layer 1
    k_agg<<<AGG_BLKS, 256, 0, stream>>>(
        offsets, csr, We + NED * HC, att + HC, gatb + HC, xlq, xrq, g, part1);
    k_red<<<1, 256, 0, stream>>>(part1, AGG_BLKS, stats);
    k_mid<<<MID_BLKS, 256, 0, stream>>>(
        g, n1w + HC, n1b + HC, linW + HC * NC, linb + NC, stats, g2q, part2);
    k_red<<<1, 256, 0, stream>>>(part2, MID_BLKS, stats + 2);
    k_final<<<(N_NODES * NC + 255) / 256, 256, 0, stream>>>(
        g2q, n2w + NC, n2b + NC, stats + 2, hq, out);
}